// Round 11
// baseline (2407.160 us; speedup 1.0000x reference)
//
#include <hip/hip_runtime.h>
#include <math.h>

#define FLAG_RELU 1
#define FLAG_BIAS 2
#define FLAG_ACC  4
#define FLAG_ATOMIC 8

static constexpr int BB   = 2;
static constexpr int N0   = 10000;
static constexpr int DIN  = 1024;
static constexpr int D    = 512;
static constexpr int NH   = 8;
static constexpr int DH   = 64;
static constexpr int MM   = 256;
static constexpr int SEQ  = 10240;
static constexpr int PADR = 239;
static constexpr int NTOK = 10001;
static constexpr int LL   = 40;
static constexpr float EPS_ = 1e-5f;

typedef short short8v __attribute__((ext_vector_type(8)));
typedef float f32x4 __attribute__((ext_vector_type(4)));

__device__ __forceinline__ void atomicMaxPosF(float* addr, float v) {
    atomicMax((unsigned int*)addr, __float_as_uint(v));
}
__device__ __forceinline__ ushort f2bf(float f) {
    unsigned u = __float_as_uint(f);
    return (ushort)((u + 0x7FFFu + ((u >> 16) & 1u)) >> 16);
}
__device__ __forceinline__ float bf2f(ushort h) {
    return __uint_as_float(((unsigned)h) << 16);
}
__device__ __forceinline__ void split4(float4 f, ushort* ph, ushort* pl) {
    ushort4 hv, lv;
    hv.x = f2bf(f.x); lv.x = f2bf(f.x - bf2f(hv.x));
    hv.y = f2bf(f.y); lv.y = f2bf(f.y - bf2f(hv.y));
    hv.z = f2bf(f.z); lv.z = f2bf(f.z - bf2f(hv.z));
    hv.w = f2bf(f.w); lv.w = f2bf(f.w - bf2f(hv.w));
    *(ushort4*)ph = hv; *(ushort4*)pl = lv;
}
__device__ __forceinline__ void split8r(const float* p, short8v& h, short8v& l) {
    ushort hb[8], lb[8];
    split4(*(const float4*)p,     &hb[0], &lb[0]);
    split4(*(const float4*)(p+4), &hb[4], &lb[4]);
    h = *(short8v*)hb; l = *(short8v*)lb;
}

// ------------------------------------------------------- MFMA GEMM 128x128
__global__ __launch_bounds__(256)
void mgemm128(const float* __restrict__ A, int lda, long long sAz,
              const ushort* __restrict__ BtH, const ushort* __restrict__ BtL, int ldbt,
              float* __restrict__ C, int ldc, long long sCz, const float* __restrict__ bias,
              int M, int N, int K, int flags, int qcols, float qscale)
{
    __shared__ ushort AsH[4*128*8], AsL[4*128*8], BsH[4*128*8], BsL[4*128*8]; // 32 KB
    A += (size_t)blockIdx.z * sAz;
    C += (size_t)blockIdx.z * sCz;
    int t = threadIdx.x;
    int m0 = blockIdx.y * 128, n0 = blockIdx.x * 128;
    int w = t >> 6, lane = t & 63, q = lane >> 4, r = lane & 15;
    int wm = w >> 1, wn = w & 1;
    f32x4 acc[4][4];
    #pragma unroll
    for (int i = 0; i < 4; i++)
        #pragma unroll
        for (int j = 0; j < 4; j++) acc[i][j] = (f32x4){0.f,0.f,0.f,0.f};

    int srow = t >> 1, scg = (t & 1) * 16;
    int qg = (t & 1) * 2;
    int gm = m0 + srow;
    float4 pa0, pa1, pa2, pa3;
    uint4  pb0, pb1, pb2, pb3;
    {
        pa0 = pa1 = pa2 = pa3 = make_float4(0,0,0,0);
        if (gm < M) {
            const float* ap = A + (size_t)gm * lda + scg;
            pa0 = *(const float4*)(ap);   pa1 = *(const float4*)(ap+4);
            pa2 = *(const float4*)(ap+8); pa3 = *(const float4*)(ap+12);
        }
        size_t gb = (size_t)(n0 + srow) * ldbt + scg;
        pb0 = *(const uint4*)(BtH + gb); pb1 = *(const uint4*)(BtH + gb + 8);
        pb2 = *(const uint4*)(BtL + gb); pb3 = *(const uint4*)(BtL + gb + 8);
    }
    for (int k0 = 0; k0 < K; k0 += 32) {
        {
            ushort hb[16], lb[16];
            split4(pa0, &hb[0],  &lb[0]);
            split4(pa1, &hb[4],  &lb[4]);
            split4(pa2, &hb[8],  &lb[8]);
            split4(pa3, &hb[12], &lb[12]);
            *(uint4*)&AsH[(qg  )*1024 + srow*8] = *(uint4*)&hb[0];
            *(uint4*)&AsH[(qg+1)*1024 + srow*8] = *(uint4*)&hb[8];
            *(uint4*)&AsL[(qg  )*1024 + srow*8] = *(uint4*)&lb[0];
            *(uint4*)&AsL[(qg+1)*1024 + srow*8] = *(uint4*)&lb[8];
            *(uint4*)&BsH[(qg  )*1024 + srow*8] = pb0;
            *(uint4*)&BsH[(qg+1)*1024 + srow*8] = pb1;
            *(uint4*)&BsL[(qg  )*1024 + srow*8] = pb2;
            *(uint4*)&BsL[(qg+1)*1024 + srow*8] = pb3;
        }
        __syncthreads();
        if (k0 + 32 < K) {
            pa0 = pa1 = pa2 = pa3 = make_float4(0,0,0,0);
            if (gm < M) {
                const float* ap = A + (size_t)gm * lda + k0 + 32 + scg;
                pa0 = *(const float4*)(ap);   pa1 = *(const float4*)(ap+4);
                pa2 = *(const float4*)(ap+8); pa3 = *(const float4*)(ap+12);
            }
            size_t gb = (size_t)(n0 + srow) * ldbt + k0 + 32 + scg;
            pb0 = *(const uint4*)(BtH + gb); pb1 = *(const uint4*)(BtH + gb + 8);
            pb2 = *(const uint4*)(BtL + gb); pb3 = *(const uint4*)(BtL + gb + 8);
        }
        short8v ah[4], al[4];
        #pragma unroll
        for (int mi = 0; mi < 4; mi++) {
            int row = wm*64 + mi*16 + r;
            ah[mi] = *(const short8v*)&AsH[q*1024 + row*8];
            al[mi] = *(const short8v*)&AsL[q*1024 + row*8];
        }
        #pragma unroll
        for (int ni = 0; ni < 4; ni++) {
            int col = wn*64 + ni*16 + r;
            short8v bh = *(const short8v*)&BsH[q*1024 + col*8];
            short8v bl = *(const short8v*)&BsL[q*1024 + col*8];
            #pragma unroll
            for (int mi = 0; mi < 4; mi++) {
                acc[mi][ni] = __builtin_amdgcn_mfma_f32_16x16x32_bf16(ah[mi], bh, acc[mi][ni], 0,0,0);
                acc[mi][ni] = __builtin_amdgcn_mfma_f32_16x16x32_bf16(ah[mi], bl, acc[mi][ni], 0,0,0);
                acc[mi][ni] = __builtin_amdgcn_mfma_f32_16x16x32_bf16(al[mi], bh, acc[mi][ni], 0,0,0);
            }
        }
        __syncthreads();
    }
    #pragma unroll
    for (int mi = 0; mi < 4; mi++)
        #pragma unroll
        for (int ni = 0; ni < 4; ni++) {
            int gcol = n0 + wn*64 + ni*16 + r;
            float qs = (gcol < qcols) ? qscale : 1.f;
            float bv = (flags & FLAG_BIAS) ? bias[gcol] : 0.f;
            #pragma unroll
            for (int rg = 0; rg < 4; rg++) {
                int grow = m0 + wm*64 + mi*16 + q*4 + rg;
                if (grow >= M) continue;
                float v = acc[mi][ni][rg] * qs + bv;
                if (flags & FLAG_RELU) v = fmaxf(v, 0.f);
                float* cp = C + (size_t)grow * ldc + gcol;
                if (flags & FLAG_ACC) v += *cp;
                *cp = v;
            }
        }
}

// ------------------------------------------------------- MFMA batched 64x64
// rowM/rowI (optional): apply exp(a - rowM[zi*MM+row]) * rowI[..] to A during
// staging (softmax folded into the GEMM's A-operand).
__global__ __launch_bounds__(256)
void mbgemm64(const float* __restrict__ Abase, long long sAb, long long sAh, long long sAz, int lda,
              const ushort* __restrict__ BtH, const ushort* __restrict__ BtL,
              const float* __restrict__ Bnt, long long sBb, long long sBh, int ldb,
              float* __restrict__ Cbase, long long sCb, long long sCh, long long sCz, int ldc,
              ushort* __restrict__ eTH, ushort* __restrict__ eTL, long long sT, int ldct,
              const float* __restrict__ rowM, const float* __restrict__ rowI,
              int M, int N, int K, int nchunk,
              float dg, float bsc, float osc, int slab0, int flags)
{
    __shared__ ushort AsH[4*64*8], AsL[4*64*8], BsH[4*64*8], BsL[4*64*8]; // 16 KB
    int zi = blockIdx.z / nchunk, ch = blockIdx.z % nchunk;
    int g = slab0 + zi, b = g >> 3, h = g & 7;
    const float* A = Abase + (size_t)b*sAb + (size_t)h*sAh + (size_t)zi*sAz;
    float* C = Cbase ? (Cbase + (size_t)b*sCb + (size_t)h*sCh + (size_t)zi*sCz) : nullptr;
    int kpc = K / nchunk;
    int kb = ch * kpc, ke = kb + kpc;
    int t = threadIdx.x;
    int m0 = blockIdx.y * 64, n0 = blockIdx.x * 64;
    int w = t >> 6, lane = t & 63, q = lane >> 4, r = lane & 15;
    int wm = w >> 1, wn = w & 1;
    f32x4 acc[2][2];
    #pragma unroll
    for (int i = 0; i < 2; i++)
        #pragma unroll
        for (int j = 0; j < 2; j++) acc[i][j] = (f32x4){0.f,0.f,0.f,0.f};

    int srow = t >> 2, scg = (t & 3) * 8;
    int qg = t & 3;
    float rmv = 0.f, riv = 1.f;
    bool doexp = (rowM != nullptr);
    if (doexp) {
        rmv = rowM[(size_t)zi * MM + m0 + srow];
        riv = rowI[(size_t)zi * MM + m0 + srow];
    }
    const float* Abp = Bnt ? (Bnt + (size_t)b*sBb + (size_t)h*sBh) : nullptr;
    float4 pa0, pa1;
    float4 pf0, pf1;
    uint4  pu0, pu1;
    {
        const float* ap = A + (size_t)(m0 + srow) * lda + kb + scg;
        pa0 = *(const float4*)ap; pa1 = *(const float4*)(ap+4);
        if (Bnt) {
            const float* bp = Abp + (size_t)(n0 + srow) * ldb + kb + scg;
            pf0 = *(const float4*)bp; pf1 = *(const float4*)(bp+4);
        } else {
            size_t gb = (size_t)b*sBb + (size_t)h*sBh + (size_t)(n0 + srow) * ldb + kb + scg;
            pu0 = *(const uint4*)(BtH + gb); pu1 = *(const uint4*)(BtL + gb);
        }
    }
    for (int k0 = kb; k0 < ke; k0 += 32) {
        {
            float4 qa0 = pa0, qa1 = pa1;
            if (doexp) {
                qa0.x = expf(qa0.x - rmv) * riv; qa0.y = expf(qa0.y - rmv) * riv;
                qa0.z = expf(qa0.z - rmv) * riv; qa0.w = expf(qa0.w - rmv) * riv;
                qa1.x = expf(qa1.x - rmv) * riv; qa1.y = expf(qa1.y - rmv) * riv;
                qa1.z = expf(qa1.z - rmv) * riv; qa1.w = expf(qa1.w - rmv) * riv;
            }
            ushort hb[8], lb[8];
            split4(qa0, &hb[0], &lb[0]);
            split4(qa1, &hb[4], &lb[4]);
            *(uint4*)&AsH[qg*512 + srow*8] = *(uint4*)&hb[0];
            *(uint4*)&AsL[qg*512 + srow*8] = *(uint4*)&lb[0];
            if (Bnt) {
                ushort hc[8], lc[8];
                split4(pf0, &hc[0], &lc[0]);
                split4(pf1, &hc[4], &lc[4]);
                *(uint4*)&BsH[qg*512 + srow*8] = *(uint4*)&hc[0];
                *(uint4*)&BsL[qg*512 + srow*8] = *(uint4*)&lc[0];
            } else {
                *(uint4*)&BsH[qg*512 + srow*8] = pu0;
                *(uint4*)&BsL[qg*512 + srow*8] = pu1;
            }
        }
        __syncthreads();
        if (k0 + 32 < ke) {
            const float* ap = A + (size_t)(m0 + srow) * lda + k0 + 32 + scg;
            pa0 = *(const float4*)ap; pa1 = *(const float4*)(ap+4);
            if (Bnt) {
                const float* bp = Abp + (size_t)(n0 + srow) * ldb + k0 + 32 + scg;
                pf0 = *(const float4*)bp; pf1 = *(const float4*)(bp+4);
            } else {
                size_t gb = (size_t)b*sBb + (size_t)h*sBh + (size_t)(n0 + srow) * ldb + k0 + 32 + scg;
                pu0 = *(const uint4*)(BtH + gb); pu1 = *(const uint4*)(BtL + gb);
            }
        }
        short8v ah[2], al[2];
        #pragma unroll
        for (int mi = 0; mi < 2; mi++) {
            int row = wm*32 + mi*16 + r;
            ah[mi] = *(const short8v*)&AsH[q*512 + row*8];
            al[mi] = *(const short8v*)&AsL[q*512 + row*8];
        }
        #pragma unroll
        for (int ni = 0; ni < 2; ni++) {
            int col = wn*32 + ni*16 + r;
            short8v bh = *(const short8v*)&BsH[q*512 + col*8];
            short8v bl = *(const short8v*)&BsL[q*512 + col*8];
            #pragma unroll
            for (int mi = 0; mi < 2; mi++) {
                acc[mi][ni] = __builtin_amdgcn_mfma_f32_16x16x32_bf16(ah[mi], bh, acc[mi][ni], 0,0,0);
                acc[mi][ni] = __builtin_amdgcn_mfma_f32_16x16x32_bf16(ah[mi], bl, acc[mi][ni], 0,0,0);
                acc[mi][ni] = __builtin_amdgcn_mfma_f32_16x16x32_bf16(al[mi], bh, acc[mi][ni], 0,0,0);
            }
        }
        __syncthreads();
    }
    bool dgnz = (dg != 0.f);
    #pragma unroll
    for (int mi = 0; mi < 2; mi++)
        #pragma unroll
        for (int ni = 0; ni < 2; ni++) {
            int gm0 = m0 + wm*32 + mi*16 + q*4;
            int gn  = n0 + wn*32 + ni*16 + r;
            float v[4];
            #pragma unroll
            for (int rg = 0; rg < 4; rg++) {
                float u = bsc * acc[mi][ni][rg];
                if (dgnz) u += dg * A[(size_t)(gm0+rg) * lda + gn];
                v[rg] = osc * u;
            }
            if (C) {
                if (flags & FLAG_ATOMIC) {
                    #pragma unroll
                    for (int rg = 0; rg < 4; rg++)
                        atomicAdd(C + (size_t)(gm0+rg) * ldc + gn, v[rg]);
                } else {
                    #pragma unroll
                    for (int rg = 0; rg < 4; rg++)
                        C[(size_t)(gm0+rg) * ldc + gn] = v[rg];
                }
            }
            if (eTH) {
                ushort4 hv, lv;
                hv.x = f2bf(v[0]); lv.x = f2bf(v[0] - bf2f(hv.x));
                hv.y = f2bf(v[1]); lv.y = f2bf(v[1] - bf2f(hv.y));
                hv.z = f2bf(v[2]); lv.z = f2bf(v[2] - bf2f(hv.z));
                hv.w = f2bf(v[3]); lv.w = f2bf(v[3] - bf2f(hv.w));
                size_t to = (size_t)g * sT + (size_t)gn * ldct + gm0;
                *(ushort4*)(eTH + to) = hv;
                *(ushort4*)(eTL + to) = lv;
            }
        }
}

// --------------------------------------------- fused a1 v2 (32-token tiles)
// grid(SEQ/32, 16 slabs), 256 thr. Phase1: wave w computes S cols w*64..+63
// for 32 tokens; softmax via quad shuffles + cross-wave LDS; P (unnorm exp)
// -> LDS col-major stride 35 (conflict-free). Phase2: wave (wm,wn) computes
// O rows wm*16..+15, d cols wn*32..+31; WB B-frags straight from L2.
__global__ __launch_bounds__(256)
void a1_fused(const float* __restrict__ qkv,
              const ushort* __restrict__ klH, const ushort* __restrict__ klL,
              const ushort* __restrict__ wbH, const ushort* __restrict__ wbL,
              float* __restrict__ attn)
{
    __shared__ float Pc[256*35];      // 35 KB
    __shared__ float redm[4][32];
    __shared__ float reds[4][32];
    int g = blockIdx.y, b = g >> 3, h = g & 7;
    int tok0 = blockIdx.x * 32;
    int t = threadIdx.x;
    int w = t >> 6, lane = t & 63, q = lane >> 4, r = lane & 15;

    // ---- phase 1: S tile (32 tokens x 64 cols per wave)
    f32x4 acc[2][4];
    #pragma unroll
    for (int i = 0; i < 2; i++)
        #pragma unroll
        for (int j = 0; j < 4; j++) acc[i][j] = (f32x4){0.f,0.f,0.f,0.f};
    #pragma unroll
    for (int k0 = 0; k0 < 64; k0 += 32) {
        short8v ah[2], al[2];
        #pragma unroll
        for (int mi = 0; mi < 2; mi++) {
            const float* ap = qkv + ((size_t)b*SEQ + tok0 + mi*16 + r) * 1536
                            + h*DH + k0 + q*8;
            split8r(ap, ah[mi], al[mi]);
        }
        #pragma unroll
        for (int ni = 0; ni < 4; ni++) {
            size_t kb = ((size_t)g*MM + w*64 + ni*16 + r) * DH + k0 + q*8;
            short8v bh = *(const short8v*)(klH + kb);
            short8v bl = *(const short8v*)(klL + kb);
            #pragma unroll
            for (int mi = 0; mi < 2; mi++) {
                acc[mi][ni] = __builtin_amdgcn_mfma_f32_16x16x32_bf16(ah[mi], bh, acc[mi][ni], 0,0,0);
                acc[mi][ni] = __builtin_amdgcn_mfma_f32_16x16x32_bf16(ah[mi], bl, acc[mi][ni], 0,0,0);
                acc[mi][ni] = __builtin_amdgcn_mfma_f32_16x16x32_bf16(al[mi], bh, acc[mi][ni], 0,0,0);
            }
        }
    }
    // ---- row max (per wave, then cross-wave)
    #pragma unroll
    for (int mi = 0; mi < 2; mi++)
        #pragma unroll
        for (int rg = 0; rg < 4; rg++) {
            float m = fmaxf(fmaxf(acc[mi][0][rg], acc[mi][1][rg]),
                            fmaxf(acc[mi][2][rg], acc[mi][3][rg]));
            for (int o = 8; o > 0; o >>= 1) m = fmaxf(m, __shfl_xor(m, o));
            if (r == 0) redm[w][mi*16 + q*4 + rg] = m;
        }
    __syncthreads();
    // ---- exp (unnormalized), partial sums, P to LDS
    #pragma unroll
    for (int mi = 0; mi < 2; mi++)
        #pragma unroll
        for (int rg = 0; rg < 4; rg++) {
            int row = mi*16 + q*4 + rg;
            float gm = fmaxf(fmaxf(redm[0][row], redm[1][row]),
                             fmaxf(redm[2][row], redm[3][row]));
            float s = 0.f;
            #pragma unroll
            for (int ni = 0; ni < 4; ni++) {
                float e = expf(acc[mi][ni][rg] - gm);
                acc[mi][ni][rg] = e;
                s += e;
            }
            for (int o = 8; o > 0; o >>= 1) s += __shfl_xor(s, o);
            if (r == 0) reds[w][row] = s;
        }
    #pragma unroll
    for (int mi = 0; mi < 2; mi++)
        #pragma unroll
        for (int ni = 0; ni < 4; ni++) {
            int col = w*64 + ni*16 + r;
            int row0 = mi*16 + q*4;
            float* pp = &Pc[col*35 + row0];
            *(float2*)(pp)     = make_float2(acc[mi][ni][0], acc[mi][ni][1]);
            *(float2*)(pp + 2) = make_float2(acc[mi][ni][2], acc[mi][ni][3]);
        }
    __syncthreads();
    // ---- phase 2: wave (wm=w&1 row-half, wn=w>>1 d-half); K=256
    int wm = w & 1, wn = w >> 1;
    f32x4 oacc[2];
    #pragma unroll
    for (int ni = 0; ni < 2; ni++) oacc[ni] = (f32x4){0.f,0.f,0.f,0.f};
    for (int k0 = 0; k0 < 8; k0++) {
        short8v ph, pl;
        {
            ushort hb[8], lb[8];
            #pragma unroll
            for (int j = 0; j < 8; j++) {
                int k = k0*32 + q*8 + j;
                float p = Pc[k*35 + wm*16 + r];
                hb[j] = f2bf(p); lb[j] = f2bf(p - bf2f(hb[j]));
            }
            ph = *(short8v*)hb; pl = *(short8v*)lb;
        }
        #pragma unroll
        for (int ni = 0; ni < 2; ni++) {
            size_t wo = ((size_t)g*64 + wn*32 + ni*16 + r) * MM + k0*32 + q*8;
            short8v bh = *(const short8v*)(wbH + wo);
            short8v bl = *(const short8v*)(wbL + wo);
            oacc[ni] = __builtin_amdgcn_mfma_f32_16x16x32_bf16(ph, bh, oacc[ni], 0,0,0);
            oacc[ni] = __builtin_amdgcn_mfma_f32_16x16x32_bf16(ph, bl, oacc[ni], 0,0,0);
            oacc[ni] = __builtin_amdgcn_mfma_f32_16x16x32_bf16(pl, bh, oacc[ni], 0,0,0);
        }
    }
    float inv[4];
    #pragma unroll
    for (int rg = 0; rg < 4; rg++) {
        int row = wm*16 + q*4 + rg;
        inv[rg] = 1.0f / (reds[0][row] + reds[1][row] + reds[2][row] + reds[3][row]);
    }
    #pragma unroll
    for (int ni = 0; ni < 2; ni++)
        #pragma unroll
        for (int rg = 0; rg < 4; rg++) {
            int tok = tok0 + wm*16 + q*4 + rg;
            attn[((size_t)b*SEQ + tok) * D + h*DH + wn*32 + ni*16 + r] = oacc[ni][rg] * inv[rg];
        }
}

// ---------------------------------- transpose + split fp32 (RxC) -> bf16 (CxR)
__global__ __launch_bounds__(256)
void convsplitT(const float* __restrict__ in, ushort* __restrict__ oh, ushort* __restrict__ ol,
                int R, int C, int ldin, long long sInB, long long sInH, long long sInZ,
                int ldo, long long sOutZ)
{
    __shared__ float tile[32][33];
    int z = blockIdx.z, b = z >> 3, h = z & 7;
    const float* I = in + (size_t)b*sInB + (size_t)h*sInH + (size_t)z*sInZ;
    int p0 = blockIdx.x * 32, c0 = blockIdx.y * 32;
    int tx = threadIdx.x & 31, ty = threadIdx.x >> 5;
    #pragma unroll
    for (int k = 0; k < 4; k++) {
        int rr = p0 + ty + k*8, cc = c0 + tx;
        tile[ty + k*8][tx] = (rr < R && cc < C) ? I[(size_t)rr * ldin + cc] : 0.f;
    }
    __syncthreads();
    #pragma unroll
    for (int k = 0; k < 4; k++) {
        int rr = p0 + tx, cc = c0 + ty + k*8;
        if (rr < R && cc < C) {
            float f = tile[tx][ty + k*8];
            ushort hv = f2bf(f);
            size_t o = (size_t)z * sOutZ + (size_t)cc * ldo + rr;
            oh[o] = hv; ol[o] = f2bf(f - bf2f(hv));
        }
    }
}

// ---------------------------------------------------------------- small ops
__global__ void fill_cls(const float* __restrict__ cls, float* __restrict__ H) {
    H[(size_t)blockIdx.x * NTOK * D + threadIdx.x] = cls[threadIdx.x];
}

__global__ __launch_bounds__(256)
void ln_pad(const float* __restrict__ H, const float* __restrict__ g,
            const float* __restrict__ bt, float* __restrict__ out)
{
    int blk = blockIdx.x;
    int b = blk / SEQ, i = blk % SEQ;
    int t = threadIdx.x;
    float* orow = out + (size_t)blk * D;
    if (i < PADR) { orow[t] = 0.f; orow[t+256] = 0.f; return; }
    const float* x = H + ((size_t)b * NTOK + (i - PADR)) * D;
    float v0 = x[t], v1 = x[t+256];
    __shared__ float w1[4], w2[4];
    float s = v0 + v1;
    for (int o = 32; o > 0; o >>= 1) s += __shfl_xor(s, o);
    if ((t & 63) == 0) w1[t >> 6] = s;
    __syncthreads();
    float mu = (w1[0]+w1[1]+w1[2]+w1[3]) * (1.0f / D);
    float d0 = v0 - mu, d1 = v1 - mu;
    float qq = d0*d0 + d1*d1;
    for (int o = 32; o > 0; o >>= 1) qq += __shfl_xor(qq, o);
    if ((t & 63) == 0) w2[t >> 6] = qq;
    __syncthreads();
    float rs = rsqrtf((w2[0]+w2[1]+w2[2]+w2[3]) * (1.0f / D) + EPS_);
    orow[t]     = d0 * rs * g[t]     + bt[t];
    orow[t+256] = d1 * rs * g[t+256] + bt[t+256];
}

__global__ __launch_bounds__(512)
void landmarks(const float* __restrict__ qkv, float* __restrict__ ql,
               float* __restrict__ klt, ushort* __restrict__ klH, ushort* __restrict__ klL)
{
    int blk = blockIdx.x;
    int b = blk >> 8, m = blk & 255;
    int c = threadIdx.x;
    const float* base = qkv + ((size_t)b * SEQ + (size_t)m * LL) * 1536;
    float sq0=0,sq1=0,sq2=0,sq3=0, sk0=0,sk1=0,sk2=0,sk3=0;
    for (int tt = 0; tt < LL; tt += 4) {
        const float* rr = base + (size_t)tt * 1536;
        sq0 += rr[c];          sk0 += rr[512 + c];
        sq1 += rr[1536 + c];   sk1 += rr[1536 + 512 + c];
        sq2 += rr[3072 + c];   sk2 += rr[3072 + 512 + c];
        sq3 += rr[4608 + c];   sk3 += rr[4608 + 512 + c];
    }
    float sq = (sq0+sq1+sq2+sq3) * (1.0f / LL);
    float sk = (sk0+sk1+sk2+sk3) * (1.0f / LL);
    int h = c >> 6, d = c & 63;
    int slab = b * NH + h;
    ql [((size_t)slab * MM + m) * DH + d] = sq;
    klt[((size_t)slab * DH + d) * MM + m] = sk;
    size_t kidx = ((size_t)slab * MM + m) * DH + d;
    ushort kh = f2bf(sk);
    klH[kidx] = kh; klL[kidx] = f2bf(sk - bf2f(kh));
}

__global__ __launch_bounds__(256)
void s2_softmax(const float* __restrict__ ql, const float* __restrict__ klt,
                float* __restrict__ a2)
{
    int blk = blockIdx.x;
    int m = blk & 255, slab = blk >> 8;
    int j = threadIdx.x;
    __shared__ float q[64];
    __shared__ float red[256];
    if (j < 64) q[j] = ql[((size_t)slab * MM + m) * DH + j];
    __syncthreads();
    const float* kt = klt + (size_t)slab * DH * MM;
    float s = 0.f;
    #pragma unroll 8
    for (int kk = 0; kk < 64; kk++) s = fmaf(q[kk], kt[kk*MM + j], s);
    red[j] = s; __syncthreads();
    for (int o = 128; o > 0; o >>= 1) { if (j < o) red[j] = fmaxf(red[j], red[j+o]); __syncthreads(); }
    float mx = red[0]; __syncthreads();
    float e = expf(s - mx);
    red[j] = e; __syncthreads();
    for (int o = 128; o > 0; o >>= 1) { if (j < o) red[j] += red[j+o]; __syncthreads(); }
    a2[((size_t)slab * MM + m) * MM + j] = e / red[0];
}

__global__ void zero_scr(float* s) { if (threadIdx.x < 2) s[threadIdx.x] = 0.f; }

__global__ __launch_bounds__(256)
void a2_alpha(const float* __restrict__ a2, float* __restrict__ scr)
{
    int slab = blockIdx.x, t = threadIdx.x;
    const float* A = a2 + (size_t)slab * MM * MM;
    float cs = 0.f, rs = 0.f;
    for (int rr = 0; rr < MM; rr++) cs += fabsf(A[(size_t)rr * MM + t]);
    for (int cc = 0; cc < MM; cc++) rs += fabsf(A[(size_t)t * MM + cc]);
    __shared__ float red[256];
    red[t] = rs; __syncthreads();
    for (int o = 128; o > 0; o >>= 1) { if (t < o) red[t] = fmaxf(red[t], red[t+o]); __syncthreads(); }
    float mrs = red[0]; __syncthreads();
    red[t] = cs; __syncthreads();
    for (int o = 128; o > 0; o >>= 1) { if (t < o) red[t] = fmaxf(red[t], red[t+o]); __syncthreads(); }
    float mcs = red[0];
    if (t == 0) { atomicMaxPosF(scr + 0, mrs); atomicMaxPosF(scr + 1, mcs); }
}

__global__ __launch_bounds__(256)
void z_init(const float* __restrict__ a2, const float* __restrict__ scr,
            float* __restrict__ z, ushort* __restrict__ zTh, ushort* __restrict__ zTl)
{
    size_t idx = (size_t)blockIdx.x * 256 + threadIdx.x;
    int slab = (int)(idx >> 16), rr = (int)((idx >> 8) & 255), cc = (int)(idx & 255);
    float inv = 1.0f / (scr[0] * scr[1]);
    z[idx] = a2[((size_t)slab << 16) + (size_t)cc * MM + rr] * inv;
    float tv = a2[idx] * inv;
    ushort th = f2bf(tv);
    zTh[idx] = th; zTl[idx] = f2bf(tv - bf2f(th));
}

// row max + inverse-sum over SEQ (no write-back of probabilities)
__global__ __launch_bounds__(256)
void s3_maxsum(const float* __restrict__ s3, float* __restrict__ rowM,
               float* __restrict__ rowI)
{
    const float* row = s3 + (size_t)blockIdx.x * SEQ;
    int t = threadIdx.x;
    float4 v[10];
    #pragma unroll
    for (int i = 0; i < 10; i++) v[i] = *(const float4*)(row + 4*(i*256 + t));
    float mx = -3.4e38f;
    #pragma unroll
    for (int i = 0; i < 10; i++)
        mx = fmaxf(mx, fmaxf(fmaxf(v[i].x, v[i].y), fmaxf(v[i].z, v[i].w)));
    __shared__ float red[4];
    for (int o = 32; o > 0; o >>= 1) mx = fmaxf(mx, __shfl_xor(mx, o));
    if ((t & 63) == 0) red[t >> 6] = mx;
    __syncthreads();
    mx = fmaxf(fmaxf(red[0], red[1]), fmaxf(red[2], red[3]));
    float sum = 0.f;
    #pragma unroll
    for (int i = 0; i < 10; i++) {
        sum += expf(v[i].x - mx) + expf(v[i].y - mx)
             + expf(v[i].z - mx) + expf(v[i].w - mx);
    }
    __shared__ float red2[4];
    for (int o = 32; o > 0; o >>= 1) sum += __shfl_xor(sum, o);
    if ((t & 63) == 0) red2[t >> 6] = sum;
    __syncthreads();
    if (t == 0) {
        rowM[blockIdx.x] = mx;
        rowI[blockIdx.x] = 1.0f / (red2[0] + red2[1] + red2[2] + red2[3]);
    }
}

__global__ __launch_bounds__(512)
void res_add(const float* __restrict__ qkv, const float* __restrict__ rw,
             float* __restrict__ attn)
{
    int blk = blockIdx.x;
    int b = blk / (SEQ/16), i0 = (blk % (SEQ/16)) * 16;
    int c = threadIdx.x, h = c >> 6;
    __shared__ float w[NH*33];
    if (c < NH*33) w[c] = rw[c];
    __syncthreads();
    float acc[16];
    float* ab = attn + ((size_t)b * SEQ + i0) * D + c;
    #pragma unroll
    for (int rr = 0; rr < 16; rr++) acc[rr] = ab[(size_t)rr * D];
    const float* vb = qkv + (size_t)b * SEQ * 1536 + 2*D + c;
    const float* wh = w + h * 33;
    #pragma unroll 4
    for (int jj = 0; jj < 48; jj++) {
        int j = i0 + jj - 16;
        float val = ((unsigned)j < (unsigned)SEQ) ? vb[(size_t)j * 1536] : 0.f;
        #pragma unroll
        for (int rr = 0; rr < 16; rr++) {
            int ky = jj - rr;
            if (ky >= 0 && ky < 33) acc[rr] = fmaf(val, wh[ky], acc[rr]);
        }
    }
    #pragma unroll
    for (int rr = 0; rr < 16; rr++) ab[(size_t)rr * D] = acc[rr];
}

// ---------------------------------------------------------------- PPEG
__global__ __launch_bounds__(256)
void t_fw(const float* __restrict__ H, float* __restrict__ P)
{
    __shared__ float tile[32][33];
    int p0 = blockIdx.x * 32, c0 = blockIdx.y * 32, b = blockIdx.z;
    int tx = threadIdx.x & 31, ty = threadIdx.x >> 5;
    #pragma unroll
    for (int k = 0; k < 4; k++) {
        int pos = p0 + ty + k*8;
        tile[ty + k*8][tx] = (pos < 10000)
            ? H[((size_t)b * NTOK + 1 + pos) * D + c0 + tx] : 0.f;
    }
    __syncthreads();
    #pragma unroll
    for (int k = 0; k < 4; k++) {
        int c = c0 + ty + k*8, pos = p0 + tx;
        if (pos < 10000)
            P[((size_t)b * D + c) * 10000 + pos] = tile[tx][ty + k*8];
    }
}

__global__ __launch_bounds__(256)
void ppeg_conv(const float* __restrict__ P,
               const float* __restrict__ w7, const float* __restrict__ b7,
               const float* __restrict__ w5, const float* __restrict__ b5,
               const float* __restrict__ w3, const float* __restrict__ b3,
               float* __restrict__ Q)
{
    __shared__ float PS[106 * 107];
    __shared__ float w7s[49], w5s[25], w3s[9];
    int blk = blockIdx.x;
    int b = blk >> 9, c = blk & 511;
    int t = threadIdx.x;
    for (int idx = t; idx < 106*107; idx += 256) PS[idx] = 0.f;
    if (t < 49) w7s[t] = w7[(size_t)c * 49 + t];
    if (t < 25) w5s[t] = w5[(size_t)c * 25 + t];
    if (t < 9)  w3s[t] = w3[(size_t)c * 9 + t];
    float bsum = b7[c] + b5[c] + b3[c];
    __syncthreads();
    const float* Pin = P + ((size_t)b * D + c) * 10000;
    for (int p = t; p < 10000; p += 256) {
        int y = p / 100, x = p - y * 100;
        PS[(y + 3) * 107 + x + 3] = Pin[p];
    }
    __syncthreads();
    float* Qo = Q + ((size_t)b * D + c) * 10000;
    for (int task = t; task < 2500; task += 256) {
        int ry = task / 100, x = task - ry * 100;
        int y0 = ry * 4;
        float a0 = bsum + PS[(y0+3)*107 + x+3];
        float a1 = bsum + PS[(y0+4)*107 + x+3];
        float a2 = bsum + PS[(y0+5)*107 + x+3];
        float a3 = bsum + PS[(y0+6)*107 + x+3];
        #pragma unroll
        for (int rr = 0; rr < 10; rr++) {
            const float* rp = &PS[(y0 + rr) * 107 + x];
            #pragma unroll
            for (int kx = 0; kx < 7; kx++) {
                float v = rp[kx];
                if (rr < 7)            a0 = fmaf(v, w7s[rr*7 + kx], a0);
                if (rr >= 1 && rr < 8) a1 = fmaf(v, w7s[(rr-1)*7 + kx], a1);
                if (rr >= 2 && rr < 9) a2 = fmaf(v, w7s[(rr-2)*7 + kx], a2);
                if (rr >= 3)           a3 = fmaf(v, w7s[(rr-3)*7 + kx], a3);
            }
        }
        #pragma unroll
        for (int rr = 0; rr < 8; rr++) {
            const float* rp = &PS[(y0 + rr + 1) * 107 + x + 1];
            #pragma unroll
            for (int kx = 0; kx < 5; kx++) {
                float v = rp[kx];
                if (rr < 5)            a0 = fmaf(v, w5s[rr*5 + kx], a0);
                if (rr >= 1 && rr < 6) a1 = fmaf(v, w5s[(rr-1)*5 + kx], a1);
                if (rr >= 2 && rr < 7) a2 = fmaf(v, w5s[(rr-2)*5 + kx], a2);
                if (rr >= 3)           a3 = fmaf(v, w5s[(rr-3)*5 + kx], a3);
            }
        }
        #pragma unroll
        for (int rr = 0; rr < 6; rr++) {
            const float* rp = &PS[(y0 + rr + 2) * 107 + x + 2];
            #pragma unroll
            for (int kx = 0; kx < 3; kx++) {
                float v = rp[kx];
                if (rr < 3)            a0 = fmaf(v, w3s[rr*3 + kx], a0);
                if (rr >= 1 && rr < 4) a1 = fmaf(v, w3s[(rr-1)*3 + kx], a1);
                if (rr >= 2 && rr < 5) a2 = fmaf(v, w3s[(rr-2)*3 + kx], a2);
                if (rr >= 3)           a3 = fmaf(v, w3s[(rr-3)*3 + kx], a3);
            }
        }
        Qo[(y0+0)*100 + x] = a0;
        Qo[(y0+1)*100 + x] = a1;
        Qo[(y0+2)*100 + x] = a2;
        Qo[(y0+3)*100 + x] = a3;
    }
}

__global__ __launch_bounds__(256)
void t_bw(const float* __restrict__ Q, float* __restrict__ H)
{
    __shared__ float tile[32][33];
    int p0 = blockIdx.x * 32, c0 = blockIdx.y * 32, b = blockIdx.z;
    int tx = threadIdx.x & 31, ty = threadIdx.x >> 5;
    #pragma unroll
    for (int k = 0; k < 4; k++) {
        int c = c0 + ty + k*8, pos = p0 + tx;
        tile[ty + k*8][tx] = (pos < 10000)
            ? Q[((size_t)b * D + c) * 10000 + pos] : 0.f;
    }
    __syncthreads();
    #pragma unroll
    for (int k = 0; k < 4; k++) {
        int pos = p0 + ty + k*8;
        if (pos < 10000)
            H[((size_t)b * NTOK + 1 + pos) * D + c0 + tx] = tile[tx][ty + k*8];
    }
}

__global__ __launch_bounds__(512)
void final_head(const float* __restrict__ H, const float* __restrict__ g,
                const float* __restrict__ bt, const float* __restrict__ w2,
                const float* __restrict__ b2, float* __restrict__ out)
{
    int b = blockIdx.x, t = threadIdx.x;
    __shared__ float red[512];
    float v = H[(size_t)b * NTOK * D + t];
    red[t] = v; __syncthreads();
    for (int o = 256; o > 0; o >>= 1) { if (t < o) red[t] += red[t+o]; __syncthreads(); }
    float mu = red[0] * (1.0f / D); __syncthreads();
    float dv = v - mu;
    red[t] = dv*dv; __syncthreads();
    for (int o = 256; o > 0; o >>= 1) { if (t < o) red[t] += red[t+o]; __syncthreads(); }
    float rstd = rsqrtf(red[0] * (1.0f / D) + EPS_); __syncthreads();
    float xn = dv * rstd * g[t] + bt[t];
    red[t] = xn * w2[2*t]; __syncthreads();
    for (int o = 256; o > 0; o >>= 1) { if (t < o) red[t] += red[t+o]; __syncthreads(); }
    float l0 = red[0] + b2[0]; __syncthreads();
    red[t] = xn * w2[2*t+1]; __syncthreads();
    for (int o = 256; o > 0; o >>= 1) { if (t < o) red[t] += red[t+o]; __syncthreads(); }
    float l1 = red[0] + b2[1];
    if (t == 0) {
        out[b*2+0] = l0; out[b*2+1] = l1;
        float mx = fmaxf(l0, l1);
        float e0 = expf(l0 - mx), e1 = expf(l1 - mx);
        float ssum = e0 + e1;
        out[4 + b*2 + 0] = e0 / ssum;
        out[4 + b*2 + 1] = e1 / ssum;
        out[8 + b] = (l1 > l0) ? 1.0f : 0.0f;
    }
}

// ---------------------------------------------------------------------------
extern "C" void kernel_launch(void* const* d_in, const int* in_sizes, int n_in,
                              void* d_out, int out_size, void* d_ws, size_t ws_size,
                              hipStream_t stream)
{
    const float* x      = (const float*)d_in[0];
    const float* w_fc1  = (const float*)d_in[1];
    const float* b_fc1  = (const float*)d_in[2];
    const float* cls    = (const float*)d_in[3];
    const float* ln1_g  = (const float*)d_in[4];
    const float* ln1_b  = (const float*)d_in[5];
    const float* qkv1_w = (const float*)d_in[6];
    const float* out1_w = (const float*)d_in[7];
    const float* out1_b = (const float*)d_in[8];
    const float* res1_w = (const float*)d_in[9];
    const float* ln2_g  = (const float*)d_in[10];
    const float* ln2_b  = (const float*)d_in[11];
    const float* qkv2_w = (const float*)d_in[12];
    const float* out2_w = (const float*)d_in[13];
    const float* out2_b = (const float*)d_in[14];
    const float* res2_w = (const float*)d_in[15];
    const float* pw7 = (const float*)d_in[16];
    const float* pb7 = (const float*)d_in[17];
    const float* pw5 = (const float*)d_in[18];
    const float* pb5 = (const float*)d_in[19];
    const float* pw3 = (const float*)d_in[20];
    const float* pb3 = (const float*)d_in[21];
    const float* lnf_g = (const float*)d_in[22];
    const float* lnf_b = (const float*)d_in[23];
    const float* w_fc2 = (const float*)d_in[24];
    const float* b_fc2 = (const float*)d_in[25];

    // workspace carve-up — R4-proven layout + 16 KB ROWM/ROWI (≈320.96 MB)
    float* ws = (float*)d_ws;
    size_t off = 0;
    auto alloc = [&](size_t n) { float* p = ws + off; off += (n + 63) & ~(size_t)63; return p; };
    float* H    = alloc((size_t)BB * NTOK * D);
    float* LN   = alloc((size_t)BB * SEQ * D);
    float* QKV  = alloc((size_t)BB * SEQ * 3 * D);
    float* QL   = alloc((size_t)BB * NH * MM * DH);
    float* KLT  = alloc((size_t)BB * NH * DH * MM);
    float* A2   = alloc((size_t)BB * NH * MM * MM);
    float* ZA   = alloc((size_t)BB * NH * MM * MM);
    float* ZB   = alloc((size_t)BB * NH * MM * MM);
    float* XZ   = alloc((size_t)BB * NH * MM * MM);
    float* A3V  = alloc((size_t)BB * NH * MM * DH);
    float* WB   = alloc((size_t)BB * NH * MM * DH);
    float* S3   = alloc((size_t)8 * MM * SEQ);
    float* SCR  = alloc(64);
    float* ROWM = alloc((size_t)8 * MM);     // per-grp row max
    float* ROWI = alloc((size_t)8 * MM);     // per-grp row inv-sum
    auto ualloc = [&](size_t n) { ushort* p = (ushort*)(ws + off); off += ((n + 127) / 2) & ~(size_t)63; return p; };
    ushort* WTfcH = ualloc((size_t)512 * 1024);
    ushort* WTfcL = ualloc((size_t)512 * 1024);
    ushort* WTqH  = ualloc((size_t)1536 * 512);
    ushort* WTqL  = ualloc((size_t)1536 * 512);
    ushort* WToH  = ualloc((size_t)512 * 512);
    ushort* WToL  = ualloc((size_t)512 * 512);
    ushort* klBH  = ualloc((size_t)16 * MM * DH);
    ushort* klBL  = ualloc((size_t)16 * MM * DH);
    float*  ATTN = LN;
    ushort* VTH  = (ushort*)LN;
    ushort* VTL  = VTH + (size_t)16 * DH * SEQ;
    ushort* A3VTH = (ushort*)ZB;
    ushort* A3VTL = A3VTH + (size_t)16 * DH * MM;
    ushort* WBTH  = A3VTL + (size_t)16 * DH * MM;
    ushort* WBTL  = WBTH  + (size_t)16 * DH * MM;
    ushort* PT   = (ushort*)S3;
    const size_t PS_ = (size_t)16 * 65536;
    ushort* zTAH = PT;            ushort* zTAL = PT + PS_;
    ushort* zTBH = PT + 2*PS_;    ushort* zTBL = PT + 3*PS_;
    ushort* XZTH = PT + 4*PS_;    ushort* XZTL = PT + 5*PS_;
    ushort* T1TH = PT + 6*PS_;    ushort* T1TL = PT + 7*PS_;
    ushort* T2TH = PT + 8*PS_;    ushort* T2TL = PT + 9*PS_;
    (void)ws_size; (void)in_sizes; (void)n_in; (void)out_size;

    // 0) fc1 weight prep + fc1 (batched over B via grid.z)
    convsplitT<<<dim3(32,16,1), 256, 0, stream>>>(w_fc1, WTfcH, WTfcL, 1024, 512, 512, 0,0,0, 1024, 0);
    mgemm128<<<dim3(4, 79, BB), 256, 0, stream>>>(x, DIN, (long long)N0*DIN,
        WTfcH, WTfcL, 1024, H + D, D, (long long)NTOK*D, b_fc1,
        N0, D, DIN, FLAG_BIAS|FLAG_RELU, 0, 1.f);
    fill_cls<<<BB, D, 0, stream>>>(cls, H);

    auto attention = [&](const float* lg, const float* lb,
                         const float* qw, const float* ow,
                         const float* ob, const float* rw)
    {
        convsplitT<<<dim3(16,48,1), 256, 0, stream>>>(qw, WTqH, WTqL, 512, 1536, 1536, 0,0,0, 512, 0);
        convsplitT<<<dim3(16,16,1), 256, 0, stream>>>(ow, WToH, WToL, 512, 512, 512, 0,0,0, 512, 0);
        ln_pad<<<BB*SEQ, 256, 0, stream>>>(H, lg, lb, LN);
        mgemm128<<<dim3(12, 160, 1), 256, 0, stream>>>(LN, D, 0, WTqH, WTqL, D,
            QKV, 3*D, 0, nullptr, BB*SEQ, 3*D, D, 0, D, 0.125f);
        convsplitT<<<dim3(320, 2, 16), 256, 0, stream>>>(QKV + 2*D, VTH, VTL,
            SEQ, DH, 1536, (long long)SEQ*1536, 64, 0, SEQ, (long long)DH*SEQ);
        landmarks<<<BB*MM, 512, 0, stream>>>(QKV, QL, KLT, klBH, klBL);
        s2_softmax<<<BB*NH*MM, 256, 0, stream>>>(QL, KLT, A2);
        zero_scr<<<1, 64, 0, stream>>>(SCR);
        a2_alpha<<<BB*NH, 256, 0, stream>>>(A2, SCR);
        z_init<<<BB*NH*MM*MM/256, 256, 0, stream>>>(A2, SCR, ZA, zTAH, zTAL);
        // Newton-Schulz: 24 batched dispatches
        float* z = ZA; float* zn = ZB;
        ushort *zTcH = zTAH, *zTcL = zTAL, *zTnH = zTBH, *zTnL = zTBL;
        for (int it = 0; it < 6; it++) {
            dim3 g(4, 4, 16);
            mbgemm64<<<g,256,0,stream>>>(A2, 0,0,65536LL, MM,
                zTcH, zTcL, nullptr, 8LL*65536, 65536LL, MM,
                XZ, 0,0,65536LL, MM, XZTH, XZTL, 65536LL, MM,
                nullptr, nullptr,
                MM, MM, MM, 1, 0.f, 1.f, 1.f, 0, 0);
            mbgemm64<<<g,256,0,stream>>>(XZ, 0,0,65536LL, MM,
                XZTH, XZTL, nullptr, 8LL*65536, 65536LL, MM,
                nullptr, 0,0,0, MM, T1TH, T1TL, 65536LL, MM,
                nullptr, nullptr,
                MM, MM, MM, 1, 7.f, -1.f, 1.f, 0, 0);
            mbgemm64<<<g,256,0,stream>>>(XZ, 0,0,65536LL, MM,
                T1TH, T1TL, nullptr, 8LL*65536, 65536LL, MM,
                nullptr, 0,0,0, MM, T2TH, T2TL, 65536LL, MM,
                nullptr, nullptr,
                MM, MM, MM, 1, 15.f, -1.f, 1.f, 0, 0);
            mbgemm64<<<g,256,0,stream>>>(z, 0,0,65536LL, MM,
                T2TH, T2TL, nullptr, 8LL*65536, 65536LL, MM,
                zn, 0,0,65536LL, MM, zTnH, zTnL, 65536LL, MM,
                nullptr, nullptr,
                MM, MM, MM, 1, 13.f, -1.f, 0.25f, 0, 0);
            float* ts = z; z = zn; zn = ts;
            ushort* uh = zTcH; zTcH = zTnH; zTnH = uh;
            ushort* ul = zTcL; zTcL = zTnL; zTnL = ul;
        }
        // z ends in ZA; ZB free for A3VT/WBT aliases
        for (int grp = 0; grp < 2; grp++) {
            int slab0 = grp * 8;
            mbgemm64<<<dim3(160, 4, 8), 256, 0, stream>>>(QL, 8LL*16384, 16384LL, 0, DH,
                nullptr, nullptr, QKV + D, (long long)SEQ*1536, 64LL, 1536,
                S3, 0,0,(long long)MM*SEQ, SEQ, nullptr, nullptr, 0, 0,
                nullptr, nullptr,
                MM, SEQ, DH, 1, 0.f, 1.f, 1.f, slab0, 0);
            s3_maxsum<<<8*MM, 256, 0, stream>>>(S3, ROWM, ROWI);
            hipMemsetAsync(A3V + (size_t)slab0 * MM * DH, 0,
                           (size_t)8 * MM * DH * sizeof(float), stream);
            // A3V += softmax(S3) @ v   (exp folded into A-staging)
            mbgemm64<<<dim3(1, 4, 8*16), 256, 0, stream>>>(S3, 0,0,(long long)MM*SEQ, SEQ,
                VTH, VTL, nullptr, 8LL*DH*SEQ, (long long)DH*SEQ, SEQ,
                A3V, 8LL*16384, 16384LL, 0, DH, nullptr, nullptr, 0, 0,
                ROWM, ROWI,
                MM, DH, SEQ, 16, 0.f, 1.f, 1.f, slab0, FLAG_ATOMIC);
        }
        convsplitT<<<dim3(8, 2, 16), 256, 0, stream>>>(A3V, A3VTH, A3VTL,
            MM, DH, DH, 0, 0, 16384LL, MM, 16384LL);
        mbgemm64<<<dim3(1, 4, 16), 256, 0, stream>>>(z, 0,0,65536LL, MM,
            A3VTH, A3VTL, nullptr, 8LL*16384, 16384LL, MM,
            WB, 8LL*16384, 16384LL, 0, DH, WBTH, WBTL, 16384LL, MM,
            nullptr, nullptr,
            MM, DH, MM, 1, 0.f, 1.f, 1.f, 0, 0);
        // fused a1 (32-token tiles)
        a1_fused<<<dim3(SEQ/32, 16), 256, 0, stream>>>(QKV, klBH, klBL, WBTH, WBTL, ATTN);
        res_add<<<BB*SEQ/16, 512, 0, stream>>>(QKV, rw, ATTN);
        mgemm128<<<dim3(4, 79, BB), 256, 0, stream>>>(ATTN + (size_t)PADR*D, D, (long long)SEQ*D,
            WToH, WToL, D, H, D, (long long)NTOK*D, ob,
            NTOK, D, D, FLAG_BIAS|FLAG_ACC, 0, 1.f);
    };

    attention(ln1_g, ln1_b, qkv1_w, out1_w, out1_b, res1_w);

    {   // PPEG (planes inside S3 region)
        float* Pp = S3;
        float* Qp = S3 + (size_t)BB * D * 10000;
        dim3 tg((10000 + 31)/32, D/32, BB);
        t_fw<<<tg, 256, 0, stream>>>(H, Pp);
        ppeg_conv<<<BB*D, 256, 0, stream>>>(Pp, pw7, pb7, pw5, pb5, pw3, pb3, Qp);
        t_bw<<<tg, 256, 0, stream>>>(Qp, H);
    }

    attention(ln2_g, ln2_b, qkv2_w, out2_w, out2_b, res2_w);

    final_head<<<BB, 512, 0, stream>>>(H, lnf_g, lnf_b, w_fc2, b_fc2, (float*)d_out);
}

// Round 12
// 2340.369 us; speedup vs baseline: 1.0285x; 1.0285x over previous
//
#include <hip/hip_runtime.h>
#include <math.h>

#define FLAG_RELU 1
#define FLAG_BIAS 2
#define FLAG_ACC  4
#define FLAG_ATOMIC 8

static constexpr int BB   = 2;
static constexpr int N0   = 10000;
static constexpr int DIN  = 1024;
static constexpr int D    = 512;
static constexpr int NH   = 8;
static constexpr int DH   = 64;
static constexpr int MM   = 256;
static constexpr int SEQ  = 10240;
static constexpr int PADR = 239;
static constexpr int NTOK = 10001;
static constexpr int LL   = 40;
static constexpr float EPS_ = 1e-5f;

typedef short short8v __attribute__((ext_vector_type(8)));
typedef float f32x4 __attribute__((ext_vector_type(4)));

__device__ __forceinline__ void atomicMaxPosF(float* addr, float v) {
    atomicMax((unsigned int*)addr, __float_as_uint(v));
}
__device__ __forceinline__ ushort f2bf(float f) {
    unsigned u = __float_as_uint(f);
    return (ushort)((u + 0x7FFFu + ((u >> 16) & 1u)) >> 16);
}
__device__ __forceinline__ float bf2f(ushort h) {
    return __uint_as_float(((unsigned)h) << 16);
}
__device__ __forceinline__ void split4(float4 f, ushort* ph, ushort* pl) {
    ushort4 hv, lv;
    hv.x = f2bf(f.x); lv.x = f2bf(f.x - bf2f(hv.x));
    hv.y = f2bf(f.y); lv.y = f2bf(f.y - bf2f(hv.y));
    hv.z = f2bf(f.z); lv.z = f2bf(f.z - bf2f(hv.z));
    hv.w = f2bf(f.w); lv.w = f2bf(f.w - bf2f(hv.w));
    *(ushort4*)ph = hv; *(ushort4*)pl = lv;
}
__device__ __forceinline__ void split8r(const float* p, short8v& h, short8v& l) {
    ushort hb[8], lb[8];
    split4(*(const float4*)p,     &hb[0], &lb[0]);
    split4(*(const float4*)(p+4), &hb[4], &lb[4]);
    h = *(short8v*)hb; l = *(short8v*)lb;
}

// ------------------------------------------------------- MFMA GEMM 128x128
__global__ __launch_bounds__(256)
void mgemm128(const float* __restrict__ A, int lda, long long sAz,
              const ushort* __restrict__ BtH, const ushort* __restrict__ BtL, int ldbt,
              float* __restrict__ C, int ldc, long long sCz, const float* __restrict__ bias,
              int M, int N, int K, int flags, int qcols, float qscale)
{
    __shared__ ushort AsH[4*128*8], AsL[4*128*8], BsH[4*128*8], BsL[4*128*8]; // 32 KB
    A += (size_t)blockIdx.z * sAz;
    C += (size_t)blockIdx.z * sCz;
    int t = threadIdx.x;
    int m0 = blockIdx.y * 128, n0 = blockIdx.x * 128;
    int w = t >> 6, lane = t & 63, q = lane >> 4, r = lane & 15;
    int wm = w >> 1, wn = w & 1;
    f32x4 acc[4][4];
    #pragma unroll
    for (int i = 0; i < 4; i++)
        #pragma unroll
        for (int j = 0; j < 4; j++) acc[i][j] = (f32x4){0.f,0.f,0.f,0.f};

    int srow = t >> 1, scg = (t & 1) * 16;
    int qg = (t & 1) * 2;
    int gm = m0 + srow;
    float4 pa0, pa1, pa2, pa3;
    uint4  pb0, pb1, pb2, pb3;
    {
        pa0 = pa1 = pa2 = pa3 = make_float4(0,0,0,0);
        if (gm < M) {
            const float* ap = A + (size_t)gm * lda + scg;
            pa0 = *(const float4*)(ap);   pa1 = *(const float4*)(ap+4);
            pa2 = *(const float4*)(ap+8); pa3 = *(const float4*)(ap+12);
        }
        size_t gb = (size_t)(n0 + srow) * ldbt + scg;
        pb0 = *(const uint4*)(BtH + gb); pb1 = *(const uint4*)(BtH + gb + 8);
        pb2 = *(const uint4*)(BtL + gb); pb3 = *(const uint4*)(BtL + gb + 8);
    }
    for (int k0 = 0; k0 < K; k0 += 32) {
        {
            ushort hb[16], lb[16];
            split4(pa0, &hb[0],  &lb[0]);
            split4(pa1, &hb[4],  &lb[4]);
            split4(pa2, &hb[8],  &lb[8]);
            split4(pa3, &hb[12], &lb[12]);
            *(uint4*)&AsH[(qg  )*1024 + srow*8] = *(uint4*)&hb[0];
            *(uint4*)&AsH[(qg+1)*1024 + srow*8] = *(uint4*)&hb[8];
            *(uint4*)&AsL[(qg  )*1024 + srow*8] = *(uint4*)&lb[0];
            *(uint4*)&AsL[(qg+1)*1024 + srow*8] = *(uint4*)&lb[8];
            *(uint4*)&BsH[(qg  )*1024 + srow*8] = pb0;
            *(uint4*)&BsH[(qg+1)*1024 + srow*8] = pb1;
            *(uint4*)&BsL[(qg  )*1024 + srow*8] = pb2;
            *(uint4*)&BsL[(qg+1)*1024 + srow*8] = pb3;
        }
        __syncthreads();
        if (k0 + 32 < K) {
            pa0 = pa1 = pa2 = pa3 = make_float4(0,0,0,0);
            if (gm < M) {
                const float* ap = A + (size_t)gm * lda + k0 + 32 + scg;
                pa0 = *(const float4*)(ap);   pa1 = *(const float4*)(ap+4);
                pa2 = *(const float4*)(ap+8); pa3 = *(const float4*)(ap+12);
            }
            size_t gb = (size_t)(n0 + srow) * ldbt + k0 + 32 + scg;
            pb0 = *(const uint4*)(BtH + gb); pb1 = *(const uint4*)(BtH + gb + 8);
            pb2 = *(const uint4*)(BtL + gb); pb3 = *(const uint4*)(BtL + gb + 8);
        }
        short8v ah[4], al[4];
        #pragma unroll
        for (int mi = 0; mi < 4; mi++) {
            int row = wm*64 + mi*16 + r;
            ah[mi] = *(const short8v*)&AsH[q*1024 + row*8];
            al[mi] = *(const short8v*)&AsL[q*1024 + row*8];
        }
        #pragma unroll
        for (int ni = 0; ni < 4; ni++) {
            int col = wn*64 + ni*16 + r;
            short8v bh = *(const short8v*)&BsH[q*1024 + col*8];
            short8v bl = *(const short8v*)&BsL[q*1024 + col*8];
            #pragma unroll
            for (int mi = 0; mi < 4; mi++) {
                acc[mi][ni] = __builtin_amdgcn_mfma_f32_16x16x32_bf16(ah[mi], bh, acc[mi][ni], 0,0,0);
                acc[mi][ni] = __builtin_amdgcn_mfma_f32_16x16x32_bf16(ah[mi], bl, acc[mi][ni], 0,0,0);
                acc[mi][ni] = __builtin_amdgcn_mfma_f32_16x16x32_bf16(al[mi], bh, acc[mi][ni], 0,0,0);
            }
        }
        __syncthreads();
    }
    #pragma unroll
    for (int mi = 0; mi < 4; mi++)
        #pragma unroll
        for (int ni = 0; ni < 4; ni++) {
            int gcol = n0 + wn*64 + ni*16 + r;
            float qs = (gcol < qcols) ? qscale : 1.f;
            float bv = (flags & FLAG_BIAS) ? bias[gcol] : 0.f;
            #pragma unroll
            for (int rg = 0; rg < 4; rg++) {
                int grow = m0 + wm*64 + mi*16 + q*4 + rg;
                if (grow >= M) continue;
                float v = acc[mi][ni][rg] * qs + bv;
                if (flags & FLAG_RELU) v = fmaxf(v, 0.f);
                float* cp = C + (size_t)grow * ldc + gcol;
                if (flags & FLAG_ACC) v += *cp;
                *cp = v;
            }
        }
}

// ------------------------------------------------------- MFMA batched 64x64
// rowM/rowI (optional): apply exp(a - rowM)*rowI to A during staging.
__global__ __launch_bounds__(256)
void mbgemm64(const float* __restrict__ Abase, long long sAb, long long sAh, long long sAz, int lda,
              const ushort* __restrict__ BtH, const ushort* __restrict__ BtL,
              const float* __restrict__ Bnt, long long sBb, long long sBh, int ldb,
              float* __restrict__ Cbase, long long sCb, long long sCh, long long sCz, int ldc,
              ushort* __restrict__ eTH, ushort* __restrict__ eTL, long long sT, int ldct,
              const float* __restrict__ rowM, const float* __restrict__ rowI,
              int M, int N, int K, int nchunk,
              float dg, float bsc, float osc, int slab0, int flags)
{
    __shared__ ushort AsH[4*64*8], AsL[4*64*8], BsH[4*64*8], BsL[4*64*8]; // 16 KB
    int zi = blockIdx.z / nchunk, ch = blockIdx.z % nchunk;
    int g = slab0 + zi, b = g >> 3, h = g & 7;
    const float* A = Abase + (size_t)b*sAb + (size_t)h*sAh + (size_t)zi*sAz;
    float* C = Cbase ? (Cbase + (size_t)b*sCb + (size_t)h*sCh + (size_t)zi*sCz) : nullptr;
    int kpc = K / nchunk;
    int kb = ch * kpc, ke = kb + kpc;
    int t = threadIdx.x;
    int m0 = blockIdx.y * 64, n0 = blockIdx.x * 64;
    int w = t >> 6, lane = t & 63, q = lane >> 4, r = lane & 15;
    int wm = w >> 1, wn = w & 1;
    f32x4 acc[2][2];
    #pragma unroll
    for (int i = 0; i < 2; i++)
        #pragma unroll
        for (int j = 0; j < 2; j++) acc[i][j] = (f32x4){0.f,0.f,0.f,0.f};

    int srow = t >> 2, scg = (t & 3) * 8;
    int qg = t & 3;
    float rmv = 0.f, riv = 1.f;
    bool doexp = (rowM != nullptr);
    if (doexp) {
        rmv = rowM[(size_t)zi * MM + m0 + srow];
        riv = rowI[(size_t)zi * MM + m0 + srow];
    }
    const float* Abp = Bnt ? (Bnt + (size_t)b*sBb + (size_t)h*sBh) : nullptr;
    float4 pa0, pa1;
    float4 pf0, pf1;
    uint4  pu0, pu1;
    {
        const float* ap = A + (size_t)(m0 + srow) * lda + kb + scg;
        pa0 = *(const float4*)ap; pa1 = *(const float4*)(ap+4);
        if (Bnt) {
            const float* bp = Abp + (size_t)(n0 + srow) * ldb + kb + scg;
            pf0 = *(const float4*)bp; pf1 = *(const float4*)(bp+4);
        } else {
            size_t gb = (size_t)b*sBb + (size_t)h*sBh + (size_t)(n0 + srow) * ldb + kb + scg;
            pu0 = *(const uint4*)(BtH + gb); pu1 = *(const uint4*)(BtL + gb);
        }
    }
    for (int k0 = kb; k0 < ke; k0 += 32) {
        {
            float4 qa0 = pa0, qa1 = pa1;
            if (doexp) {
                qa0.x = expf(qa0.x - rmv) * riv; qa0.y = expf(qa0.y - rmv) * riv;
                qa0.z = expf(qa0.z - rmv) * riv; qa0.w = expf(qa0.w - rmv) * riv;
                qa1.x = expf(qa1.x - rmv) * riv; qa1.y = expf(qa1.y - rmv) * riv;
                qa1.z = expf(qa1.z - rmv) * riv; qa1.w = expf(qa1.w - rmv) * riv;
            }
            ushort hb[8], lb[8];
            split4(qa0, &hb[0], &lb[0]);
            split4(qa1, &hb[4], &lb[4]);
            *(uint4*)&AsH[qg*512 + srow*8] = *(uint4*)&hb[0];
            *(uint4*)&AsL[qg*512 + srow*8] = *(uint4*)&lb[0];
            if (Bnt) {
                ushort hc[8], lc[8];
                split4(pf0, &hc[0], &lc[0]);
                split4(pf1, &hc[4], &lc[4]);
                *(uint4*)&BsH[qg*512 + srow*8] = *(uint4*)&hc[0];
                *(uint4*)&BsL[qg*512 + srow*8] = *(uint4*)&lc[0];
            } else {
                *(uint4*)&BsH[qg*512 + srow*8] = pu0;
                *(uint4*)&BsL[qg*512 + srow*8] = pu1;
            }
        }
        __syncthreads();
        if (k0 + 32 < ke) {
            const float* ap = A + (size_t)(m0 + srow) * lda + k0 + 32 + scg;
            pa0 = *(const float4*)ap; pa1 = *(const float4*)(ap+4);
            if (Bnt) {
                const float* bp = Abp + (size_t)(n0 + srow) * ldb + k0 + 32 + scg;
                pf0 = *(const float4*)bp; pf1 = *(const float4*)(bp+4);
            } else {
                size_t gb = (size_t)b*sBb + (size_t)h*sBh + (size_t)(n0 + srow) * ldb + k0 + 32 + scg;
                pu0 = *(const uint4*)(BtH + gb); pu1 = *(const uint4*)(BtL + gb);
            }
        }
        short8v ah[2], al[2];
        #pragma unroll
        for (int mi = 0; mi < 2; mi++) {
            int row = wm*32 + mi*16 + r;
            ah[mi] = *(const short8v*)&AsH[q*512 + row*8];
            al[mi] = *(const short8v*)&AsL[q*512 + row*8];
        }
        #pragma unroll
        for (int ni = 0; ni < 2; ni++) {
            int col = wn*32 + ni*16 + r;
            short8v bh = *(const short8v*)&BsH[q*512 + col*8];
            short8v bl = *(const short8v*)&BsL[q*512 + col*8];
            #pragma unroll
            for (int mi = 0; mi < 2; mi++) {
                acc[mi][ni] = __builtin_amdgcn_mfma_f32_16x16x32_bf16(ah[mi], bh, acc[mi][ni], 0,0,0);
                acc[mi][ni] = __builtin_amdgcn_mfma_f32_16x16x32_bf16(ah[mi], bl, acc[mi][ni], 0,0,0);
                acc[mi][ni] = __builtin_amdgcn_mfma_f32_16x16x32_bf16(al[mi], bh, acc[mi][ni], 0,0,0);
            }
        }
        __syncthreads();
    }
    bool dgnz = (dg != 0.f);
    #pragma unroll
    for (int mi = 0; mi < 2; mi++)
        #pragma unroll
        for (int ni = 0; ni < 2; ni++) {
            int gm0 = m0 + wm*32 + mi*16 + q*4;
            int gn  = n0 + wn*32 + ni*16 + r;
            float v[4];
            #pragma unroll
            for (int rg = 0; rg < 4; rg++) {
                float u = bsc * acc[mi][ni][rg];
                if (dgnz) u += dg * A[(size_t)(gm0+rg) * lda + gn];
                v[rg] = osc * u;
            }
            if (C) {
                if (flags & FLAG_ATOMIC) {
                    #pragma unroll
                    for (int rg = 0; rg < 4; rg++)
                        atomicAdd(C + (size_t)(gm0+rg) * ldc + gn, v[rg]);
                } else {
                    #pragma unroll
                    for (int rg = 0; rg < 4; rg++)
                        C[(size_t)(gm0+rg) * ldc + gn] = v[rg];
                }
            }
            if (eTH) {
                ushort4 hv, lv;
                hv.x = f2bf(v[0]); lv.x = f2bf(v[0] - bf2f(hv.x));
                hv.y = f2bf(v[1]); lv.y = f2bf(v[1] - bf2f(hv.y));
                hv.z = f2bf(v[2]); lv.z = f2bf(v[2] - bf2f(hv.z));
                hv.w = f2bf(v[3]); lv.w = f2bf(v[3] - bf2f(hv.w));
                size_t to = (size_t)g * sT + (size_t)gn * ldct + gm0;
                *(ushort4*)(eTH + to) = hv;
                *(ushort4*)(eTL + to) = lv;
            }
        }
}

// --------------------------------------------- fused a1 v3 (bf16 P in LDS)
// grid(SEQ/32, 16 slabs), 256 thr. Phase1: wave w computes S cols w*64..+63
// for 32 tokens; softmax (unnorm exp); P split ONCE to bf16 hi/lo, stored
// row-major [32][264] (row stride 528 B = 33*16 -> aligned b128 frag reads,
// conflict-free). Phase2: pure ds_read_b128 + L2 WB loads + MFMA.
__global__ __launch_bounds__(256)
void a1_fused(const float* __restrict__ qkv,
              const ushort* __restrict__ klH, const ushort* __restrict__ klL,
              const ushort* __restrict__ wbH, const ushort* __restrict__ wbL,
              float* __restrict__ attn)
{
    constexpr int LP = 264;
    __shared__ ushort PcH[32*LP], PcL[32*LP];   // 16.5 KB each
    __shared__ float redm[4][32];
    __shared__ float reds[4][32];
    int g = blockIdx.y, b = g >> 3, h = g & 7;
    int tok0 = blockIdx.x * 32;
    int t = threadIdx.x;
    int w = t >> 6, lane = t & 63, q = lane >> 4, r = lane & 15;

    // ---- phase 1: S tile (32 tokens x 64 cols per wave)
    f32x4 acc[2][4];
    #pragma unroll
    for (int i = 0; i < 2; i++)
        #pragma unroll
        for (int j = 0; j < 4; j++) acc[i][j] = (f32x4){0.f,0.f,0.f,0.f};
    #pragma unroll
    for (int k0 = 0; k0 < 64; k0 += 32) {
        short8v ah[2], al[2];
        #pragma unroll
        for (int mi = 0; mi < 2; mi++) {
            const float* ap = qkv + ((size_t)b*SEQ + tok0 + mi*16 + r) * 1536
                            + h*DH + k0 + q*8;
            split8r(ap, ah[mi], al[mi]);
        }
        #pragma unroll
        for (int ni = 0; ni < 4; ni++) {
            size_t kb = ((size_t)g*MM + w*64 + ni*16 + r) * DH + k0 + q*8;
            short8v bh = *(const short8v*)(klH + kb);
            short8v bl = *(const short8v*)(klL + kb);
            #pragma unroll
            for (int mi = 0; mi < 2; mi++) {
                acc[mi][ni] = __builtin_amdgcn_mfma_f32_16x16x32_bf16(ah[mi], bh, acc[mi][ni], 0,0,0);
                acc[mi][ni] = __builtin_amdgcn_mfma_f32_16x16x32_bf16(ah[mi], bl, acc[mi][ni], 0,0,0);
                acc[mi][ni] = __builtin_amdgcn_mfma_f32_16x16x32_bf16(al[mi], bh, acc[mi][ni], 0,0,0);
            }
        }
    }
    // ---- row max (per wave, then cross-wave)
    #pragma unroll
    for (int mi = 0; mi < 2; mi++)
        #pragma unroll
        for (int rg = 0; rg < 4; rg++) {
            float m = fmaxf(fmaxf(acc[mi][0][rg], acc[mi][1][rg]),
                            fmaxf(acc[mi][2][rg], acc[mi][3][rg]));
            for (int o = 8; o > 0; o >>= 1) m = fmaxf(m, __shfl_xor(m, o));
            if (r == 0) redm[w][mi*16 + q*4 + rg] = m;
        }
    __syncthreads();
    // ---- exp (unnormalized), partial sums; P -> bf16 hi/lo in LDS
    #pragma unroll
    for (int mi = 0; mi < 2; mi++)
        #pragma unroll
        for (int rg = 0; rg < 4; rg++) {
            int row = mi*16 + q*4 + rg;
            float gm = fmaxf(fmaxf(redm[0][row], redm[1][row]),
                             fmaxf(redm[2][row], redm[3][row]));
            float s = 0.f;
            #pragma unroll
            for (int ni = 0; ni < 4; ni++) {
                float e = expf(acc[mi][ni][rg] - gm);
                acc[mi][ni][rg] = e;
                s += e;
                int col = w*64 + ni*16 + r;
                ushort hv = f2bf(e);
                PcH[row*LP + col] = hv;
                PcL[row*LP + col] = f2bf(e - bf2f(hv));
            }
            for (int o = 8; o > 0; o >>= 1) s += __shfl_xor(s, o);
            if (r == 0) reds[w][row] = s;
        }
    __syncthreads();
    // ---- phase 2: wave (wm=w&1 row-half, wn=w>>1 d-half); K=256
    int wm = w & 1, wn = w >> 1;
    int prow = wm*16 + r;
    f32x4 oacc[2];
    #pragma unroll
    for (int ni = 0; ni < 2; ni++) oacc[ni] = (f32x4){0.f,0.f,0.f,0.f};
    #pragma unroll
    for (int k0 = 0; k0 < 8; k0++) {
        short8v ph = *(const short8v*)&PcH[prow*LP + k0*32 + q*8];
        short8v pl = *(const short8v*)&PcL[prow*LP + k0*32 + q*8];
        #pragma unroll
        for (int ni = 0; ni < 2; ni++) {
            size_t wo = ((size_t)g*64 + wn*32 + ni*16 + r) * MM + k0*32 + q*8;
            short8v bh = *(const short8v*)(wbH + wo);
            short8v bl = *(const short8v*)(wbL + wo);
            oacc[ni] = __builtin_amdgcn_mfma_f32_16x16x32_bf16(ph, bh, oacc[ni], 0,0,0);
            oacc[ni] = __builtin_amdgcn_mfma_f32_16x16x32_bf16(ph, bl, oacc[ni], 0,0,0);
            oacc[ni] = __builtin_amdgcn_mfma_f32_16x16x32_bf16(pl, bh, oacc[ni], 0,0,0);
        }
    }
    float inv[4];
    #pragma unroll
    for (int rg = 0; rg < 4; rg++) {
        int row = wm*16 + q*4 + rg;
        inv[rg] = 1.0f / (reds[0][row] + reds[1][row] + reds[2][row] + reds[3][row]);
    }
    #pragma unroll
    for (int ni = 0; ni < 2; ni++)
        #pragma unroll
        for (int rg = 0; rg < 4; rg++) {
            int tok = tok0 + wm*16 + q*4 + rg;
            attn[((size_t)b*SEQ + tok) * D + h*DH + wn*32 + ni*16 + r] = oacc[ni][rg] * inv[rg];
        }
}

// ---------------------------------- transpose + split fp32 (RxC) -> bf16 (CxR)
__global__ __launch_bounds__(256)
void convsplitT(const float* __restrict__ in, ushort* __restrict__ oh, ushort* __restrict__ ol,
                int R, int C, int ldin, long long sInB, long long sInH, long long sInZ,
                int ldo, long long sOutZ)
{
    __shared__ float tile[32][33];
    int z = blockIdx.z, b = z >> 3, h = z & 7;
    const float* I = in + (size_t)b*sInB + (size_t)h*sInH + (size_t)z*sInZ;
    int p0 = blockIdx.x * 32, c0 = blockIdx.y * 32;
    int tx = threadIdx.x & 31, ty = threadIdx.x >> 5;
    #pragma unroll
    for (int k = 0; k < 4; k++) {
        int rr = p0 + ty + k*8, cc = c0 + tx;
        tile[ty + k*8][tx] = (rr < R && cc < C) ? I[(size_t)rr * ldin + cc] : 0.f;
    }
    __syncthreads();
    #pragma unroll
    for (int k = 0; k < 4; k++) {
        int rr = p0 + tx, cc = c0 + ty + k*8;
        if (rr < R && cc < C) {
            float f = tile[tx][ty + k*8];
            ushort hv = f2bf(f);
            size_t o = (size_t)z * sOutZ + (size_t)cc * ldo + rr;
            oh[o] = hv; ol[o] = f2bf(f - bf2f(hv));
        }
    }
}

// ---------------------------------------------------------------- small ops
__global__ void fill_cls(const float* __restrict__ cls, float* __restrict__ H) {
    H[(size_t)blockIdx.x * NTOK * D + threadIdx.x] = cls[threadIdx.x];
}

__global__ __launch_bounds__(256)
void ln_pad(const float* __restrict__ H, const float* __restrict__ g,
            const float* __restrict__ bt, float* __restrict__ out)
{
    int blk = blockIdx.x;
    int b = blk / SEQ, i = blk % SEQ;
    int t = threadIdx.x;
    float* orow = out + (size_t)blk * D;
    if (i < PADR) { orow[t] = 0.f; orow[t+256] = 0.f; return; }
    const float* x = H + ((size_t)b * NTOK + (i - PADR)) * D;
    float v0 = x[t], v1 = x[t+256];
    __shared__ float w1[4], w2[4];
    float s = v0 + v1;
    for (int o = 32; o > 0; o >>= 1) s += __shfl_xor(s, o);
    if ((t & 63) == 0) w1[t >> 6] = s;
    __syncthreads();
    float mu = (w1[0]+w1[1]+w1[2]+w1[3]) * (1.0f / D);
    float d0 = v0 - mu, d1 = v1 - mu;
    float qq = d0*d0 + d1*d1;
    for (int o = 32; o > 0; o >>= 1) qq += __shfl_xor(qq, o);
    if ((t & 63) == 0) w2[t >> 6] = qq;
    __syncthreads();
    float rs = rsqrtf((w2[0]+w2[1]+w2[2]+w2[3]) * (1.0f / D) + EPS_);
    orow[t]     = d0 * rs * g[t]     + bt[t];
    orow[t+256] = d1 * rs * g[t+256] + bt[t+256];
}

__global__ __launch_bounds__(512)
void landmarks(const float* __restrict__ qkv, float* __restrict__ ql,
               float* __restrict__ klt, ushort* __restrict__ klH, ushort* __restrict__ klL)
{
    int blk = blockIdx.x;
    int b = blk >> 8, m = blk & 255;
    int c = threadIdx.x;
    const float* base = qkv + ((size_t)b * SEQ + (size_t)m * LL) * 1536;
    float sq0=0,sq1=0,sq2=0,sq3=0, sk0=0,sk1=0,sk2=0,sk3=0;
    for (int tt = 0; tt < LL; tt += 4) {
        const float* rr = base + (size_t)tt * 1536;
        sq0 += rr[c];          sk0 += rr[512 + c];
        sq1 += rr[1536 + c];   sk1 += rr[1536 + 512 + c];
        sq2 += rr[3072 + c];   sk2 += rr[3072 + 512 + c];
        sq3 += rr[4608 + c];   sk3 += rr[4608 + 512 + c];
    }
    float sq = (sq0+sq1+sq2+sq3) * (1.0f / LL);
    float sk = (sk0+sk1+sk2+sk3) * (1.0f / LL);
    int h = c >> 6, d = c & 63;
    int slab = b * NH + h;
    ql [((size_t)slab * MM + m) * DH + d] = sq;
    klt[((size_t)slab * DH + d) * MM + m] = sk;
    size_t kidx = ((size_t)slab * MM + m) * DH + d;
    ushort kh = f2bf(sk);
    klH[kidx] = kh; klL[kidx] = f2bf(sk - bf2f(kh));
}

__global__ __launch_bounds__(256)
void s2_softmax(const float* __restrict__ ql, const float* __restrict__ klt,
                float* __restrict__ a2)
{
    int blk = blockIdx.x;
    int m = blk & 255, slab = blk >> 8;
    int j = threadIdx.x;
    __shared__ float q[64];
    __shared__ float red[256];
    if (j < 64) q[j] = ql[((size_t)slab * MM + m) * DH + j];
    __syncthreads();
    const float* kt = klt + (size_t)slab * DH * MM;
    float s = 0.f;
    #pragma unroll 8
    for (int kk = 0; kk < 64; kk++) s = fmaf(q[kk], kt[kk*MM + j], s);
    red[j] = s; __syncthreads();
    for (int o = 128; o > 0; o >>= 1) { if (j < o) red[j] = fmaxf(red[j], red[j+o]); __syncthreads(); }
    float mx = red[0]; __syncthreads();
    float e = expf(s - mx);
    red[j] = e; __syncthreads();
    for (int o = 128; o > 0; o >>= 1) { if (j < o) red[j] += red[j+o]; __syncthreads(); }
    a2[((size_t)slab * MM + m) * MM + j] = e / red[0];
}

__global__ void zero_scr(float* s) { if (threadIdx.x < 2) s[threadIdx.x] = 0.f; }

__global__ __launch_bounds__(256)
void a2_alpha(const float* __restrict__ a2, float* __restrict__ scr)
{
    int slab = blockIdx.x, t = threadIdx.x;
    const float* A = a2 + (size_t)slab * MM * MM;
    float cs = 0.f, rs = 0.f;
    for (int rr = 0; rr < MM; rr++) cs += fabsf(A[(size_t)rr * MM + t]);
    for (int cc = 0; cc < MM; cc++) rs += fabsf(A[(size_t)t * MM + cc]);
    __shared__ float red[256];
    red[t] = rs; __syncthreads();
    for (int o = 128; o > 0; o >>= 1) { if (t < o) red[t] = fmaxf(red[t], red[t+o]); __syncthreads(); }
    float mrs = red[0]; __syncthreads();
    red[t] = cs; __syncthreads();
    for (int o = 128; o > 0; o >>= 1) { if (t < o) red[t] = fmaxf(red[t], red[t+o]); __syncthreads(); }
    float mcs = red[0];
    if (t == 0) { atomicMaxPosF(scr + 0, mrs); atomicMaxPosF(scr + 1, mcs); }
}

__global__ __launch_bounds__(256)
void z_init(const float* __restrict__ a2, const float* __restrict__ scr,
            float* __restrict__ z, ushort* __restrict__ zTh, ushort* __restrict__ zTl)
{
    size_t idx = (size_t)blockIdx.x * 256 + threadIdx.x;
    int slab = (int)(idx >> 16), rr = (int)((idx >> 8) & 255), cc = (int)(idx & 255);
    float inv = 1.0f / (scr[0] * scr[1]);
    z[idx] = a2[((size_t)slab << 16) + (size_t)cc * MM + rr] * inv;
    float tv = a2[idx] * inv;
    ushort th = f2bf(tv);
    zTh[idx] = th; zTl[idx] = f2bf(tv - bf2f(th));
}

// row max + inverse-sum over SEQ (no write-back of probabilities)
__global__ __launch_bounds__(256)
void s3_maxsum(const float* __restrict__ s3, float* __restrict__ rowM,
               float* __restrict__ rowI)
{
    const float* row = s3 + (size_t)blockIdx.x * SEQ;
    int t = threadIdx.x;
    float4 v[10];
    #pragma unroll
    for (int i = 0; i < 10; i++) v[i] = *(const float4*)(row + 4*(i*256 + t));
    float mx = -3.4e38f;
    #pragma unroll
    for (int i = 0; i < 10; i++)
        mx = fmaxf(mx, fmaxf(fmaxf(v[i].x, v[i].y), fmaxf(v[i].z, v[i].w)));
    __shared__ float red[4];
    for (int o = 32; o > 0; o >>= 1) mx = fmaxf(mx, __shfl_xor(mx, o));
    if ((t & 63) == 0) red[t >> 6] = mx;
    __syncthreads();
    mx = fmaxf(fmaxf(red[0], red[1]), fmaxf(red[2], red[3]));
    float sum = 0.f;
    #pragma unroll
    for (int i = 0; i < 10; i++) {
        sum += expf(v[i].x - mx) + expf(v[i].y - mx)
             + expf(v[i].z - mx) + expf(v[i].w - mx);
    }
    __shared__ float red2[4];
    for (int o = 32; o > 0; o >>= 1) sum += __shfl_xor(sum, o);
    if ((t & 63) == 0) red2[t >> 6] = sum;
    __syncthreads();
    if (t == 0) {
        rowM[blockIdx.x] = mx;
        rowI[blockIdx.x] = 1.0f / (red2[0] + red2[1] + red2[2] + red2[3]);
    }
}

__global__ __launch_bounds__(512)
void res_add(const float* __restrict__ qkv, const float* __restrict__ rw,
             float* __restrict__ attn)
{
    int blk = blockIdx.x;
    int b = blk / (SEQ/16), i0 = (blk % (SEQ/16)) * 16;
    int c = threadIdx.x, h = c >> 6;
    __shared__ float w[NH*33];
    if (c < NH*33) w[c] = rw[c];
    __syncthreads();
    float acc[16];
    float* ab = attn + ((size_t)b * SEQ + i0) * D + c;
    #pragma unroll
    for (int rr = 0; rr < 16; rr++) acc[rr] = ab[(size_t)rr * D];
    const float* vb = qkv + (size_t)b * SEQ * 1536 + 2*D + c;
    const float* wh = w + h * 33;
    #pragma unroll 4
    for (int jj = 0; jj < 48; jj++) {
        int j = i0 + jj - 16;
        float val = ((unsigned)j < (unsigned)SEQ) ? vb[(size_t)j * 1536] : 0.f;
        #pragma unroll
        for (int rr = 0; rr < 16; rr++) {
            int ky = jj - rr;
            if (ky >= 0 && ky < 33) acc[rr] = fmaf(val, wh[ky], acc[rr]);
        }
    }
    #pragma unroll
    for (int rr = 0; rr < 16; rr++) ab[(size_t)rr * D] = acc[rr];
}

// ---------------------------------------------------------------- PPEG
__global__ __launch_bounds__(256)
void t_fw(const float* __restrict__ H, float* __restrict__ P)
{
    __shared__ float tile[32][33];
    int p0 = blockIdx.x * 32, c0 = blockIdx.y * 32, b = blockIdx.z;
    int tx = threadIdx.x & 31, ty = threadIdx.x >> 5;
    #pragma unroll
    for (int k = 0; k < 4; k++) {
        int pos = p0 + ty + k*8;
        tile[ty + k*8][tx] = (pos < 10000)
            ? H[((size_t)b * NTOK + 1 + pos) * D + c0 + tx] : 0.f;
    }
    __syncthreads();
    #pragma unroll
    for (int k = 0; k < 4; k++) {
        int c = c0 + ty + k*8, pos = p0 + tx;
        if (pos < 10000)
            P[((size_t)b * D + c) * 10000 + pos] = tile[tx][ty + k*8];
    }
}

__global__ __launch_bounds__(256)
void ppeg_conv(const float* __restrict__ P,
               const float* __restrict__ w7, const float* __restrict__ b7,
               const float* __restrict__ w5, const float* __restrict__ b5,
               const float* __restrict__ w3, const float* __restrict__ b3,
               float* __restrict__ Q)
{
    __shared__ float PS[106 * 107];
    __shared__ float w7s[49], w5s[25], w3s[9];
    int blk = blockIdx.x;
    int b = blk >> 9, c = blk & 511;
    int t = threadIdx.x;
    for (int idx = t; idx < 106*107; idx += 256) PS[idx] = 0.f;
    if (t < 49) w7s[t] = w7[(size_t)c * 49 + t];
    if (t < 25) w5s[t] = w5[(size_t)c * 25 + t];
    if (t < 9)  w3s[t] = w3[(size_t)c * 9 + t];
    float bsum = b7[c] + b5[c] + b3[c];
    __syncthreads();
    const float* Pin = P + ((size_t)b * D + c) * 10000;
    for (int p = t; p < 10000; p += 256) {
        int y = p / 100, x = p - y * 100;
        PS[(y + 3) * 107 + x + 3] = Pin[p];
    }
    __syncthreads();
    float* Qo = Q + ((size_t)b * D + c) * 10000;
    for (int task = t; task < 2500; task += 256) {
        int ry = task / 100, x = task - ry * 100;
        int y0 = ry * 4;
        float a0 = bsum + PS[(y0+3)*107 + x+3];
        float a1 = bsum + PS[(y0+4)*107 + x+3];
        float a2 = bsum + PS[(y0+5)*107 + x+3];
        float a3 = bsum + PS[(y0+6)*107 + x+3];
        #pragma unroll
        for (int rr = 0; rr < 10; rr++) {
            const float* rp = &PS[(y0 + rr) * 107 + x];
            #pragma unroll
            for (int kx = 0; kx < 7; kx++) {
                float v = rp[kx];
                if (rr < 7)            a0 = fmaf(v, w7s[rr*7 + kx], a0);
                if (rr >= 1 && rr < 8) a1 = fmaf(v, w7s[(rr-1)*7 + kx], a1);
                if (rr >= 2 && rr < 9) a2 = fmaf(v, w7s[(rr-2)*7 + kx], a2);
                if (rr >= 3)           a3 = fmaf(v, w7s[(rr-3)*7 + kx], a3);
            }
        }
        #pragma unroll
        for (int rr = 0; rr < 8; rr++) {
            const float* rp = &PS[(y0 + rr + 1) * 107 + x + 1];
            #pragma unroll
            for (int kx = 0; kx < 5; kx++) {
                float v = rp[kx];
                if (rr < 5)            a0 = fmaf(v, w5s[rr*5 + kx], a0);
                if (rr >= 1 && rr < 6) a1 = fmaf(v, w5s[(rr-1)*5 + kx], a1);
                if (rr >= 2 && rr < 7) a2 = fmaf(v, w5s[(rr-2)*5 + kx], a2);
                if (rr >= 3)           a3 = fmaf(v, w5s[(rr-3)*5 + kx], a3);
            }
        }
        #pragma unroll
        for (int rr = 0; rr < 6; rr++) {
            const float* rp = &PS[(y0 + rr + 2) * 107 + x + 2];
            #pragma unroll
            for (int kx = 0; kx < 3; kx++) {
                float v = rp[kx];
                if (rr < 3)            a0 = fmaf(v, w3s[rr*3 + kx], a0);
                if (rr >= 1 && rr < 4) a1 = fmaf(v, w3s[(rr-1)*3 + kx], a1);
                if (rr >= 2 && rr < 5) a2 = fmaf(v, w3s[(rr-2)*3 + kx], a2);
                if (rr >= 3)           a3 = fmaf(v, w3s[(rr-3)*3 + kx], a3);
            }
        }
        Qo[(y0+0)*100 + x] = a0;
        Qo[(y0+1)*100 + x] = a1;
        Qo[(y0+2)*100 + x] = a2;
        Qo[(y0+3)*100 + x] = a3;
    }
}

__global__ __launch_bounds__(256)
void t_bw(const float* __restrict__ Q, float* __restrict__ H)
{
    __shared__ float tile[32][33];
    int p0 = blockIdx.x * 32, c0 = blockIdx.y * 32, b = blockIdx.z;
    int tx = threadIdx.x & 31, ty = threadIdx.x >> 5;
    #pragma unroll
    for (int k = 0; k < 4; k++) {
        int c = c0 + ty + k*8, pos = p0 + tx;
        tile[ty + k*8][tx] = (pos < 10000)
            ? Q[((size_t)b * D + c) * 10000 + pos] : 0.f;
    }
    __syncthreads();
    #pragma unroll
    for (int k = 0; k < 4; k++) {
        int pos = p0 + ty + k*8;
        if (pos < 10000)
            H[((size_t)b * NTOK + 1 + pos) * D + c0 + tx] = tile[tx][ty + k*8];
    }
}

__global__ __launch_bounds__(512)
void final_head(const float* __restrict__ H, const float* __restrict__ g,
                const float* __restrict__ bt, const float* __restrict__ w2,
                const float* __restrict__ b2, float* __restrict__ out)
{
    int b = blockIdx.x, t = threadIdx.x;
    __shared__ float red[512];
    float v = H[(size_t)b * NTOK * D + t];
    red[t] = v; __syncthreads();
    for (int o = 256; o > 0; o >>= 1) { if (t < o) red[t] += red[t+o]; __syncthreads(); }
    float mu = red[0] * (1.0f / D); __syncthreads();
    float dv = v - mu;
    red[t] = dv*dv; __syncthreads();
    for (int o = 256; o > 0; o >>= 1) { if (t < o) red[t] += red[t+o]; __syncthreads(); }
    float rstd = rsqrtf(red[0] * (1.0f / D) + EPS_); __syncthreads();
    float xn = dv * rstd * g[t] + bt[t];
    red[t] = xn * w2[2*t]; __syncthreads();
    for (int o = 256; o > 0; o >>= 1) { if (t < o) red[t] += red[t+o]; __syncthreads(); }
    float l0 = red[0] + b2[0]; __syncthreads();
    red[t] = xn * w2[2*t+1]; __syncthreads();
    for (int o = 256; o > 0; o >>= 1) { if (t < o) red[t] += red[t+o]; __syncthreads(); }
    float l1 = red[0] + b2[1];
    if (t == 0) {
        out[b*2+0] = l0; out[b*2+1] = l1;
        float mx = fmaxf(l0, l1);
        float e0 = expf(l0 - mx), e1 = expf(l1 - mx);
        float ssum = e0 + e1;
        out[4 + b*2 + 0] = e0 / ssum;
        out[4 + b*2 + 1] = e1 / ssum;
        out[8 + b] = (l1 > l0) ? 1.0f : 0.0f;
    }
}

// ---------------------------------------------------------------------------
extern "C" void kernel_launch(void* const* d_in, const int* in_sizes, int n_in,
                              void* d_out, int out_size, void* d_ws, size_t ws_size,
                              hipStream_t stream)
{
    const float* x      = (const float*)d_in[0];
    const float* w_fc1  = (const float*)d_in[1];
    const float* b_fc1  = (const float*)d_in[2];
    const float* cls    = (const float*)d_in[3];
    const float* ln1_g  = (const float*)d_in[4];
    const float* ln1_b  = (const float*)d_in[5];
    const float* qkv1_w = (const float*)d_in[6];
    const float* out1_w = (const float*)d_in[7];
    const float* out1_b = (const float*)d_in[8];
    const float* res1_w = (const float*)d_in[9];
    const float* ln2_g  = (const float*)d_in[10];
    const float* ln2_b  = (const float*)d_in[11];
    const float* qkv2_w = (const float*)d_in[12];
    const float* out2_w = (const float*)d_in[13];
    const float* out2_b = (const float*)d_in[14];
    const float* res2_w = (const float*)d_in[15];
    const float* pw7 = (const float*)d_in[16];
    const float* pb7 = (const float*)d_in[17];
    const float* pw5 = (const float*)d_in[18];
    const float* pb5 = (const float*)d_in[19];
    const float* pw3 = (const float*)d_in[20];
    const float* pb3 = (const float*)d_in[21];
    const float* lnf_g = (const float*)d_in[22];
    const float* lnf_b = (const float*)d_in[23];
    const float* w_fc2 = (const float*)d_in[24];
    const float* b_fc2 = (const float*)d_in[25];

    // workspace carve-up — R4-proven layout + 16 KB ROWM/ROWI (≈320.96 MB)
    float* ws = (float*)d_ws;
    size_t off = 0;
    auto alloc = [&](size_t n) { float* p = ws + off; off += (n + 63) & ~(size_t)63; return p; };
    float* H    = alloc((size_t)BB * NTOK * D);
    float* LN   = alloc((size_t)BB * SEQ * D);
    float* QKV  = alloc((size_t)BB * SEQ * 3 * D);
    float* QL   = alloc((size_t)BB * NH * MM * DH);
    float* KLT  = alloc((size_t)BB * NH * DH * MM);
    float* A2   = alloc((size_t)BB * NH * MM * MM);
    float* ZA   = alloc((size_t)BB * NH * MM * MM);
    float* ZB   = alloc((size_t)BB * NH * MM * MM);
    float* XZ   = alloc((size_t)BB * NH * MM * MM);
    float* A3V  = alloc((size_t)BB * NH * MM * DH);
    float* WB   = alloc((size_t)BB * NH * MM * DH);
    float* S3   = alloc((size_t)8 * MM * SEQ);
    float* SCR  = alloc(64);
    float* ROWM = alloc((size_t)8 * MM);
    float* ROWI = alloc((size_t)8 * MM);
    auto ualloc = [&](size_t n) { ushort* p = (ushort*)(ws + off); off += ((n + 127) / 2) & ~(size_t)63; return p; };
    ushort* WTfcH = ualloc((size_t)512 * 1024);
    ushort* WTfcL = ualloc((size_t)512 * 1024);
    ushort* WTqH  = ualloc((size_t)1536 * 512);
    ushort* WTqL  = ualloc((size_t)1536 * 512);
    ushort* WToH  = ualloc((size_t)512 * 512);
    ushort* WToL  = ualloc((size_t)512 * 512);
    ushort* klBH  = ualloc((size_t)16 * MM * DH);
    ushort* klBL  = ualloc((size_t)16 * MM * DH);
    float*  ATTN = LN;
    ushort* VTH  = (ushort*)LN;
    ushort* VTL  = VTH + (size_t)16 * DH * SEQ;
    ushort* A3VTH = (ushort*)ZB;
    ushort* A3VTL = A3VTH + (size_t)16 * DH * MM;
    ushort* WBTH  = A3VTL + (size_t)16 * DH * MM;
    ushort* WBTL  = WBTH  + (size_t)16 * DH * MM;
    ushort* PT   = (ushort*)S3;
    const size_t PS_ = (size_t)16 * 65536;
    ushort* zTAH = PT;            ushort* zTAL = PT + PS_;
    ushort* zTBH = PT + 2*PS_;    ushort* zTBL = PT + 3*PS_;
    ushort* XZTH = PT + 4*PS_;    ushort* XZTL = PT + 5*PS_;
    ushort* T1TH = PT + 6*PS_;    ushort* T1TL = PT + 7*PS_;
    ushort* T2TH = PT + 8*PS_;    ushort* T2TL = PT + 9*PS_;
    (void)ws_size; (void)in_sizes; (void)n_in; (void)out_size;

    // 0) fc1 weight prep + fc1 (batched over B via grid.z)
    convsplitT<<<dim3(32,16,1), 256, 0, stream>>>(w_fc1, WTfcH, WTfcL, 1024, 512, 512, 0,0,0, 1024, 0);
    mgemm128<<<dim3(4, 79, BB), 256, 0, stream>>>(x, DIN, (long long)N0*DIN,
        WTfcH, WTfcL, 1024, H + D, D, (long long)NTOK*D, b_fc1,
        N0, D, DIN, FLAG_BIAS|FLAG_RELU, 0, 1.f);
    fill_cls<<<BB, D, 0, stream>>>(cls, H);

    auto attention = [&](const float* lg, const float* lb,
                         const float* qw, const float* ow,
                         const float* ob, const float* rw)
    {
        convsplitT<<<dim3(16,48,1), 256, 0, stream>>>(qw, WTqH, WTqL, 512, 1536, 1536, 0,0,0, 512, 0);
        convsplitT<<<dim3(16,16,1), 256, 0, stream>>>(ow, WToH, WToL, 512, 512, 512, 0,0,0, 512, 0);
        ln_pad<<<BB*SEQ, 256, 0, stream>>>(H, lg, lb, LN);
        mgemm128<<<dim3(12, 160, 1), 256, 0, stream>>>(LN, D, 0, WTqH, WTqL, D,
            QKV, 3*D, 0, nullptr, BB*SEQ, 3*D, D, 0, D, 0.125f);
        convsplitT<<<dim3(320, 2, 16), 256, 0, stream>>>(QKV + 2*D, VTH, VTL,
            SEQ, DH, 1536, (long long)SEQ*1536, 64, 0, SEQ, (long long)DH*SEQ);
        landmarks<<<BB*MM, 512, 0, stream>>>(QKV, QL, KLT, klBH, klBL);
        s2_softmax<<<BB*NH*MM, 256, 0, stream>>>(QL, KLT, A2);
        zero_scr<<<1, 64, 0, stream>>>(SCR);
        a2_alpha<<<BB*NH, 256, 0, stream>>>(A2, SCR);
        z_init<<<BB*NH*MM*MM/256, 256, 0, stream>>>(A2, SCR, ZA, zTAH, zTAL);
        // Newton-Schulz: 24 batched dispatches
        float* z = ZA; float* zn = ZB;
        ushort *zTcH = zTAH, *zTcL = zTAL, *zTnH = zTBH, *zTnL = zTBL;
        for (int it = 0; it < 6; it++) {
            dim3 g(4, 4, 16);
            mbgemm64<<<g,256,0,stream>>>(A2, 0,0,65536LL, MM,
                zTcH, zTcL, nullptr, 8LL*65536, 65536LL, MM,
                XZ, 0,0,65536LL, MM, XZTH, XZTL, 65536LL, MM,
                nullptr, nullptr,
                MM, MM, MM, 1, 0.f, 1.f, 1.f, 0, 0);
            mbgemm64<<<g,256,0,stream>>>(XZ, 0,0,65536LL, MM,
                XZTH, XZTL, nullptr, 8LL*65536, 65536LL, MM,
                nullptr, 0,0,0, MM, T1TH, T1TL, 65536LL, MM,
                nullptr, nullptr,
                MM, MM, MM, 1, 7.f, -1.f, 1.f, 0, 0);
            mbgemm64<<<g,256,0,stream>>>(XZ, 0,0,65536LL, MM,
                T1TH, T1TL, nullptr, 8LL*65536, 65536LL, MM,
                nullptr, 0,0,0, MM, T2TH, T2TL, 65536LL, MM,
                nullptr, nullptr,
                MM, MM, MM, 1, 15.f, -1.f, 1.f, 0, 0);
            mbgemm64<<<g,256,0,stream>>>(z, 0,0,65536LL, MM,
                T2TH, T2TL, nullptr, 8LL*65536, 65536LL, MM,
                zn, 0,0,65536LL, MM, zTnH, zTnL, 65536LL, MM,
                nullptr, nullptr,
                MM, MM, MM, 1, 13.f, -1.f, 0.25f, 0, 0);
            float* ts = z; z = zn; zn = ts;
            ushort* uh = zTcH; zTcH = zTnH; zTnH = uh;
            ushort* ul = zTcL; zTcL = zTnL; zTnL = ul;
        }
        // z ends in ZA; ZB free for A3VT/WBT aliases
        for (int grp = 0; grp < 2; grp++) {
            int slab0 = grp * 8;
            mbgemm64<<<dim3(160, 4, 8), 256, 0, stream>>>(QL, 8LL*16384, 16384LL, 0, DH,
                nullptr, nullptr, QKV + D, (long long)SEQ*1536, 64LL, 1536,
                S3, 0,0,(long long)MM*SEQ, SEQ, nullptr, nullptr, 0, 0,
                nullptr, nullptr,
                MM, SEQ, DH, 1, 0.f, 1.f, 1.f, slab0, 0);
            s3_maxsum<<<8*MM, 256, 0, stream>>>(S3, ROWM, ROWI);
            hipMemsetAsync(A3V + (size_t)slab0 * MM * DH, 0,
                           (size_t)8 * MM * DH * sizeof(float), stream);
            mbgemm64<<<dim3(1, 4, 8*16), 256, 0, stream>>>(S3, 0,0,(long long)MM*SEQ, SEQ,
                VTH, VTL, nullptr, 8LL*DH*SEQ, (long long)DH*SEQ, SEQ,
                A3V, 8LL*16384, 16384LL, 0, DH, nullptr, nullptr, 0, 0,
                ROWM, ROWI,
                MM, DH, SEQ, 16, 0.f, 1.f, 1.f, slab0, FLAG_ATOMIC);
        }
        convsplitT<<<dim3(8, 2, 16), 256, 0, stream>>>(A3V, A3VTH, A3VTL,
            MM, DH, DH, 0, 0, 16384LL, MM, 16384LL);
        mbgemm64<<<dim3(1, 4, 16), 256, 0, stream>>>(z, 0,0,65536LL, MM,
            A3VTH, A3VTL, nullptr, 8LL*16384, 16384LL, MM,
            WB, 8LL*16384, 16384LL, 0, DH, WBTH, WBTL, 16384LL, MM,
            nullptr, nullptr,
            MM, DH, MM, 1, 0.f, 1.f, 1.f, 0, 0);
        // fused a1 v3 (bf16 P in LDS)
        a1_fused<<<dim3(SEQ/32, 16), 256, 0, stream>>>(QKV, klBH, klBL, WBTH, WBTL, ATTN);
        res_add<<<BB*SEQ/16, 512, 0, stream>>>(QKV, rw, ATTN);
        mgemm128<<<dim3(4, 79, BB), 256, 0, stream>>>(ATTN + (size_t)PADR*D, D, (long long)SEQ*D,
            WToH, WToL, D, H, D, (long long)NTOK*D, ob,
            NTOK, D, D, FLAG_BIAS|FLAG_ACC, 0, 1.f);
    };

    attention(ln1_g, ln1_b, qkv1_w, out1_w, out1_b, res1_w);

    {   // PPEG (planes inside S3 region)
        float* Pp = S3;
        float* Qp = S3 + (size_t)BB * D * 10000;
        dim3 tg((10000 + 31)/32, D/32, BB);
        t_fw<<<tg, 256, 0, stream>>>(H, Pp);
        ppeg_conv<<<BB*D, 256, 0, stream>>>(Pp, pw7, pb7, pw5, pb5, pw3, pb3, Qp);
        t_bw<<<tg, 256, 0, stream>>>(Qp, H);
    }

    attention(ln2_g, ln2_b, qkv2_w, out2_w, out2_b, res2_w);

    final_head<<<BB, 512, 0, stream>>>(H, lnf_g, lnf_b, w_fc2, b_fc2, (float*)d_out);
}